// Round 5
// baseline (20125.581 us; speedup 1.0000x reference)
//
#include <hip/hip_runtime.h>
#include <cstddef>
#include <cstdint>

// VQ-VAE 1D forward. Encoder fp64 (z_e must be fp64-accurate: reference argmin follows
// the fp32 dist formula zsq+csq-2zc with first-index ties; nv_vq_f32 emulates it and is
// kept BYTE-IDENTICAL to the round-4 passing version). Decoder fp32.
// R5: retiled conv3 kernels (64o x 128t), restored validated tiled down/in/1x1 fp64,
// decoder chunk NB=16.
// d_out: x_hat (B,T,36) | codes as float (B,512) | [loss_vq, perplexity, loss_pos, loss_dir]

#define TID ((int)threadIdx.x)
#define NB 8    // encoder batches per chunk (fp64 buffers)
#define NBD 16  // decoder batches per chunk (fp32 buffers)

__device__ __forceinline__ float silu_f(float y) { return y / (1.f + expf(-y)); }

// ================= weight prep =================
__global__ void perm_oik_iko_f64(const float* __restrict__ src, double* __restrict__ dst,
                                 int R, int O, int I, int K) {
  int n = R * O * I * K;
  for (int idx = blockIdx.x * blockDim.x + TID; idx < n; idx += gridDim.x * blockDim.x) {
    int o = idx % O;
    int k = (idx / O) % K;
    int i = (idx / (O * K)) % I;
    int r = idx / (O * K * I);
    dst[idx] = (double)src[((r * O + o) * I + i) * K + k];
  }
}

__global__ void perm_oik_iko(const float* __restrict__ src, float* __restrict__ dst,
                             int R, int O, int I, int K) {
  int n = R * O * I * K;
  for (int idx = blockIdx.x * blockDim.x + TID; idx < n; idx += gridDim.x * blockDim.x) {
    int o = idx % O;
    int k = (idx / O) % K;
    int i = (idx / (O * K)) % I;
    int r = idx / (O * K * I);
    dst[idx] = src[((r * O + o) * I + i) * K + k];
  }
}

__global__ void perm_decout(const float* __restrict__ src, float* __restrict__ dst) {
  int n = 256 * 36 * 4;
  for (int idx = blockIdx.x * blockDim.x + TID; idx < n; idx += gridDim.x * blockDim.x) {
    int k = idx & 3;
    int o = (idx >> 2) % 36;
    int i = idx / 144;
    dst[idx] = (k < 3) ? src[(o * 256 + i) * 3 + k] : 0.f;
  }
}

__global__ void zero_k(float* p, int n) {
  int i = blockIdx.x * blockDim.x + TID;
  if (i < n) p[i] = 0.f;
}

// csq[j] = fp32 sequential sum of fl(c*c)
__global__ void csq_f32(const float* __restrict__ cb, float* __restrict__ csq) {
  int j = blockIdx.x * blockDim.x + TID;
  if (j < 1024) {
    float s = 0.f;
    for (int c = 0; c < 128; c++) { float v = cb[j * 128 + c]; s += v * v; }
    csq[j] = s;
  }
}

// ================= fp64 encoder stages (tiled, validated-equivalent) =================
// input conv 36->256 fp64, reads x (B,T,36). grid=(NB*32,4)
__global__ __launch_bounds__(256) void conv_in_f64(const float* __restrict__ x, const double* __restrict__ wT,
                                                   const float* __restrict__ bias, double* __restrict__ out) {
  int b = blockIdx.x >> 5;
  int t0 = (blockIdx.x & 31) << 6;
  int o0 = blockIdx.y << 6;
  int tx = TID & 15, oy = TID >> 4;
  __shared__ double ins[36][68];
  __shared__ double wsl[36 * 192];
  for (int idx = TID; idx < 36 * 66; idx += 256) {
    int i = idx % 36, c = idx / 36;
    int t = t0 - 1 + c;
    double v = 0.;
    if (t >= 0 && t < 2048) v = (double)x[((size_t)(b * 2048 + t)) * 36 + i];
    ins[i][c] = v;
  }
  for (int idx = TID; idx < 36 * 192; idx += 256) {
    int o = idx & 63;
    int kk = (idx >> 6) % 3;
    int i = idx / 192;
    wsl[idx] = wT[(i * 3 + kk) * 256 + o0 + o];
  }
  __syncthreads();
  double acc[4][4];
#pragma unroll
  for (int m = 0; m < 4; m++)
#pragma unroll
    for (int n = 0; n < 4; n++) acc[m][n] = 0.;
  for (int i = 0; i < 36; i++) {
    double xv[6];
#pragma unroll
    for (int q = 0; q < 6; q++) xv[q] = ins[i][(tx << 2) + q];
    const double* wrow = &wsl[i * 192];
    double wv[3][4];
#pragma unroll
    for (int kk = 0; kk < 3; kk++)
#pragma unroll
      for (int m = 0; m < 4; m++) wv[kk][m] = wrow[kk * 64 + (oy << 2) + m];
#pragma unroll
    for (int m = 0; m < 4; m++)
#pragma unroll
      for (int n = 0; n < 4; n++)
        acc[m][n] += wv[0][m] * xv[n] + wv[1][m] * xv[n + 1] + wv[2][m] * xv[n + 2];
  }
  int obase = o0 + (oy << 2);
#pragma unroll
  for (int m = 0; m < 4; m++) {
    int o = obase + m;
    double bv = (double)bias[o];
    size_t rowo = (((size_t)((b << 8) + o)) << 11) + t0 + (tx << 2);
#pragma unroll
    for (int n = 0; n < 4; n++) out[rowo + n] = acc[m][n] + bv;
  }
}

// k=3 conv 256->256 fp64, RETILED: 64o x 128t, acc 4x8. grid=(NB*16,4)
__global__ __launch_bounds__(256) void conv3_f64(const double* __restrict__ in, const double* __restrict__ wT,
                                                 const float* __restrict__ bias, const double* __restrict__ src,
                                                 double* __restrict__ out) {
  int b = blockIdx.x >> 4;
  int t0 = (blockIdx.x & 15) << 7;
  int o0 = blockIdx.y << 6;
  int tx = TID & 15, oy = TID >> 4;
  __shared__ double ins[16][132];
  __shared__ double wsl[16 * 192];
  double acc[4][8];
#pragma unroll
  for (int m = 0; m < 4; m++)
#pragma unroll
    for (int n = 0; n < 8; n++) acc[m][n] = 0.;
  for (int ic0 = 0; ic0 < 256; ic0 += 16) {
    __syncthreads();
    for (int idx = TID; idx < 16 * 132; idx += 256) {
      int r = idx / 132, c = idx - r * 132;
      int t = t0 - 1 + c;
      double v = 0.;
      if (c < 130 && t >= 0 && t < 2048) v = in[(((size_t)((b << 8) + ic0 + r)) << 11) + t];
      ins[r][c] = v;
    }
    for (int idx = TID; idx < 16 * 192; idx += 256) {
      int o = idx & 63;
      int kk = (idx >> 6) % 3;
      int i = idx / 192;
      wsl[idx] = wT[((ic0 + i) * 3 + kk) * 256 + o0 + o];
    }
    __syncthreads();
#pragma unroll 2
    for (int i = 0; i < 16; i++) {
      double xv[10];
      const double* xr = &ins[i][tx << 3];
#pragma unroll
      for (int q = 0; q < 5; q++) {
        double2 d2 = *(const double2*)&xr[q * 2];
        xv[2 * q] = d2.x; xv[2 * q + 1] = d2.y;
      }
      const double* wrow = &wsl[i * 192];
      double wv[3][4];
#pragma unroll
      for (int kk = 0; kk < 3; kk++) {
        double2 a = *(const double2*)&wrow[kk * 64 + (oy << 2)];
        double2 bq = *(const double2*)&wrow[kk * 64 + (oy << 2) + 2];
        wv[kk][0] = a.x; wv[kk][1] = a.y; wv[kk][2] = bq.x; wv[kk][3] = bq.y;
      }
#pragma unroll
      for (int m = 0; m < 4; m++)
#pragma unroll
        for (int n = 0; n < 8; n++)
          acc[m][n] += wv[0][m] * xv[n] + wv[1][m] * xv[n + 1] + wv[2][m] * xv[n + 2];
    }
  }
#pragma unroll
  for (int m = 0; m < 4; m++) {
    int o = o0 + (oy << 2) + m;
    double bv = (double)bias[o];
    size_t rowo = (((size_t)((b << 8) + o)) << 11) + t0 + (tx << 3);
#pragma unroll
    for (int n = 0; n < 8; n++) {
      double v = acc[m][n] + bv;
      if (src) v += src[rowo + n];
      out[rowo + n] = v;
    }
  }
}

// down conv k=8 stride 4 fp64, Tout=512. grid=(NB*8,4)
__global__ __launch_bounds__(256) void conv_down_f64(const double* __restrict__ in, const double* __restrict__ wT,
                                                     const float* __restrict__ bias, double* __restrict__ out) {
  int b = blockIdx.x >> 3;
  int to0 = (blockIdx.x & 7) << 6;
  int o0 = blockIdx.y << 6;
  int tx = TID & 15, oy = TID >> 4;
  __shared__ double ins[8][264];
  __shared__ double wsl[8 * 512];
  double acc[4][4];
#pragma unroll
  for (int m = 0; m < 4; m++)
#pragma unroll
    for (int n = 0; n < 4; n++) acc[m][n] = 0.;
  for (int ic0 = 0; ic0 < 256; ic0 += 8) {
    __syncthreads();
    for (int idx = TID; idx < 8 * 260; idx += 256) {
      int r = idx / 260, c = idx % 260;
      int s = (to0 << 2) - 2 + c;
      double v = 0.;
      if (s >= 0 && s < 2048) v = in[(((size_t)((b << 8) + ic0 + r)) << 11) + s];
      ins[r][c] = v;
    }
    for (int idx = TID; idx < 8 * 512; idx += 256) {
      int o = idx & 63;
      int kk = (idx >> 6) & 7;
      int i = idx >> 9;
      wsl[idx] = wT[((ic0 + i) * 8 + kk) * 256 + o0 + o];
    }
    __syncthreads();
#pragma unroll
    for (int i = 0; i < 8; i++) {
      double xv[20];
#pragma unroll
      for (int q = 0; q < 20; q++) xv[q] = ins[i][(tx << 4) + q];
#pragma unroll
      for (int kk = 0; kk < 8; kk++) {
        double wv[4];
#pragma unroll
        for (int m = 0; m < 4; m++) wv[m] = wsl[(i << 9) + (kk << 6) + (oy << 2) + m];
#pragma unroll
        for (int n = 0; n < 4; n++) {
          double xval = xv[(n << 2) + kk];
#pragma unroll
          for (int m = 0; m < 4; m++) acc[m][n] += wv[m] * xval;
        }
      }
    }
  }
  int obase = o0 + (oy << 2);
#pragma unroll
  for (int m = 0; m < 4; m++) {
    int o = obase + m;
    double bv = (double)bias[o];
    size_t rowo = (((size_t)((b << 8) + o)) << 9) + to0 + (tx << 2);
#pragma unroll
    for (int n = 0; n < 4; n++) out[rowo + n] = acc[m][n] + bv;
  }
}

// 1x1 conv fp64, T=512. wIO [i][o]. grid=(NB*8, O/64)
__global__ __launch_bounds__(256) void conv1x1_f64(const double* __restrict__ in, const double* __restrict__ wIO,
                                                   const float* __restrict__ bias, double* __restrict__ out,
                                                   int Kc, int O) {
  int b = blockIdx.x >> 3;
  int t0 = (blockIdx.x & 7) << 6;
  int o0 = blockIdx.y << 6;
  int tx = TID & 15, oy = TID >> 4;
  __shared__ double xs[32][64];
  __shared__ double wsd[32][64];
  double acc[4][4];
#pragma unroll
  for (int m = 0; m < 4; m++)
#pragma unroll
    for (int n = 0; n < 4; n++) acc[m][n] = 0.;
  for (int ic0 = 0; ic0 < Kc; ic0 += 32) {
    __syncthreads();
    for (int idx = TID; idx < 2048; idx += 256) {
      int r = idx >> 6, c = idx & 63;
      xs[r][c] = in[((size_t)(b * Kc + ic0 + r) << 9) + t0 + c];
      wsd[r][c] = wIO[(ic0 + r) * O + o0 + c];
    }
    __syncthreads();
#pragma unroll 8
    for (int i = 0; i < 32; i++) {
      double xv[4], wv[4];
#pragma unroll
      for (int q = 0; q < 4; q++) { xv[q] = xs[i][(tx << 2) + q]; wv[q] = wsd[i][(oy << 2) + q]; }
#pragma unroll
      for (int m = 0; m < 4; m++)
#pragma unroll
        for (int n = 0; n < 4; n++) acc[m][n] += wv[m] * xv[n];
    }
  }
#pragma unroll
  for (int m = 0; m < 4; m++) {
    int o = o0 + (oy << 2) + m;
    double bv = (double)bias[o];
    size_t rowo = ((size_t)(b * O + o) << 9) + t0 + (tx << 2);
#pragma unroll
    for (int n = 0; n < 4; n++) out[rowo + n] = acc[m][n] + bv;
  }
}

// ===== VQ: BYTE-IDENTICAL to round-4 passing version — do not touch =====
__global__ __launch_bounds__(256) void nv_vq_f32(const double* __restrict__ zE,
                                                 const float* __restrict__ cb,
                                                 const float* __restrict__ csq,
                                                 int* __restrict__ codes) {
  int n = blockIdx.x * blockDim.x + TID;  // 16384 points
  if (n >= 16384) return;
  int b = n >> 9, t = n & 511;
  const double* zp = zE + ((size_t)b * 128) * 512 + t;
  // z vector in fp32 (reference z_e is fp32)
  float z[128];
  for (int c = 0; c < 128; c++) z[c] = (float)zp[(size_t)c * 512];
  // zsq in fp32, sequential (uniform constant across codes -> tie-robust)
  float zsq = 0.f;
  for (int c = 0; c < 128; c++) zsq += z[c] * z[c];
  float best = 3.4e38f;
  int bj = 0;
  for (int j = 0; j < 1024; j++) {
    const float* cr = cb + (size_t)j * 128;
    float zc = 0.f;
    for (int c = 0; c < 128; c++) zc += z[c] * cr[c];
    float A = zsq + csq[j];     // fl32(zsq + csq)
    float B = 2.0f * zc;        // fl32(2*zc) (exact scale)
    float d = A - B;            // fl32(A - B)
    if (d < best) { best = d; bj = j; }  // ascending j, strict < == first-min (jnp.argmin)
  }
  codes[n] = bj;
}

// ================= fp64 res-block GN =================
__global__ __launch_bounds__(256) void gn_silu_f64(const double* __restrict__ in, double* __restrict__ out,
                                                   const float* __restrict__ gamma, const float* __restrict__ beta) {
  int b = blockIdx.x >> 3, g = blockIdx.x & 7;
  size_t base = ((size_t)b * 256 + g * 32) * 2048;
  const double2* src = (const double2*)(in + base);
  double2* dst = (double2*)(out + base);
  double s1 = 0., s2 = 0.;
  for (int f = TID; f < 32768; f += 256) {
    double2 v = src[f];
    s1 += v.x + v.y;
    s2 += v.x * v.x + v.y * v.y;
  }
  __shared__ double r1[256], r2[256];
  r1[TID] = s1; r2[TID] = s2;
  __syncthreads();
  for (int st = 128; st > 0; st >>= 1) {
    if (TID < st) { r1[TID] += r1[TID + st]; r2[TID] += r2[TID + st]; }
    __syncthreads();
  }
  double mu = r1[0] * (1.0 / 65536.0);
  double var = r2[0] * (1.0 / 65536.0) - mu * mu;
  double rs = 1.0 / sqrt(var + 1e-5);
  for (int f = TID; f < 32768; f += 256) {
    int c = g * 32 + (f >> 10);
    double a = rs * (double)gamma[c];
    double bb = (double)beta[c] - mu * a;
    double2 v = src[f];
    double2 o;
    double y0 = v.x * a + bb, y1 = v.y * a + bb;
    o.x = y0 / (1.0 + exp(-y0));
    o.y = y1 / (1.0 + exp(-y1));
    dst[f] = o;
  }
}

// ================= VQ bookkeeping =================
__global__ void count_k(const int* __restrict__ codes, float* __restrict__ counts) {
  int n = blockIdx.x * blockDim.x + TID;
  if (n < 16384) atomicAdd(&counts[codes[n]], 1.f);
}

__global__ __launch_bounds__(256) void gather_f64(const float* __restrict__ cb, const int* __restrict__ codes,
                                                  const double* __restrict__ zE, float* __restrict__ zQ,
                                                  float* __restrict__ vqsum) {
  double part = 0.;
  const int total = 32 * 128 * 512;
  for (int idx = blockIdx.x * blockDim.x + TID; idx < total; idx += gridDim.x * blockDim.x) {
    int t = idx & 511;
    int c = (idx >> 9) & 127;
    int b = idx >> 16;
    int code = codes[(b << 9) + t];
    float q = cb[code * 128 + c];
    double d = (double)q - zE[idx];
    zQ[idx] = q;
    part += d * d;
  }
  __shared__ double red[256];
  red[TID] = part;
  __syncthreads();
  for (int st = 128; st > 0; st >>= 1) {
    if (TID < st) red[TID] += red[TID + st];
    __syncthreads();
  }
  if (TID == 0) atomicAdd(vqsum, (float)red[0]);
}

// ================= fp32 decoder =================
__global__ __launch_bounds__(256) void gn_silu_k(const float* __restrict__ in, float* __restrict__ out,
                                                 const float* __restrict__ gamma, const float* __restrict__ beta) {
  int b = blockIdx.x >> 3, g = blockIdx.x & 7;
  size_t base = ((size_t)b * 256 + g * 32) * 2048;
  const float4* src = (const float4*)(in + base);
  float4* dst = (float4*)(out + base);
  float s1 = 0.f, s2 = 0.f;
  for (int f = TID; f < 16384; f += 256) {
    float4 v = src[f];
    s1 += v.x + v.y + v.z + v.w;
    s2 += v.x * v.x + v.y * v.y + v.z * v.z + v.w * v.w;
  }
  __shared__ float r1[256], r2[256];
  r1[TID] = s1; r2[TID] = s2;
  __syncthreads();
  for (int st = 128; st > 0; st >>= 1) {
    if (TID < st) { r1[TID] += r1[TID + st]; r2[TID] += r2[TID + st]; }
    __syncthreads();
  }
  float mu = r1[0] * (1.f / 65536.f);
  float var = r2[0] * (1.f / 65536.f) - mu * mu;
  float rs = rsqrtf(var + 1e-5f);
  for (int f = TID; f < 16384; f += 256) {
    int c = g * 32 + (f >> 9);
    float a = rs * gamma[c];
    float bb = beta[c] - mu * a;
    float4 v = src[f];
    float4 o;
    o.x = silu_f(v.x * a + bb);
    o.y = silu_f(v.y * a + bb);
    o.z = silu_f(v.z * a + bb);
    o.w = silu_f(v.w * a + bb);
    dst[f] = o;
  }
}

// k=3 conv 256->256 fp32, RETILED: 64o x 128t, acc 4x8, K-chunk 32. grid=(NBD*16,4)
__global__ __launch_bounds__(256) void conv3_k(const float* __restrict__ in, const float* __restrict__ wT,
                                               const float* __restrict__ bias, const float* __restrict__ src,
                                               float* __restrict__ out) {
  int b = blockIdx.x >> 4;
  int t0 = (blockIdx.x & 15) << 7;
  int o0 = blockIdx.y << 6;
  int tx = TID & 15, oy = TID >> 4;
  __shared__ float ins[32][132];
  __shared__ float wsl[32 * 192];
  float acc[4][8];
#pragma unroll
  for (int m = 0; m < 4; m++)
#pragma unroll
    for (int n = 0; n < 8; n++) acc[m][n] = 0.f;
  for (int ic0 = 0; ic0 < 256; ic0 += 32) {
    __syncthreads();
    for (int idx = TID; idx < 32 * 132; idx += 256) {
      int r = idx / 132, c = idx - r * 132;
      int t = t0 - 1 + c;
      float v = 0.f;
      if (c < 130 && t >= 0 && t < 2048) v = in[(((size_t)((b << 8) + ic0 + r)) << 11) + t];
      ins[r][c] = v;
    }
    for (int idx = TID; idx < 32 * 192; idx += 256) {
      int o = idx & 63;
      int kk = (idx >> 6) % 3;
      int i = idx / 192;
      wsl[idx] = wT[((ic0 + i) * 3 + kk) * 256 + o0 + o];
    }
    __syncthreads();
#pragma unroll 4
    for (int i = 0; i < 32; i++) {
      float xv[10];
      const float* xr = &ins[i][tx << 3];
      float4 a4 = *(const float4*)&xr[0];
      float4 b4 = *(const float4*)&xr[4];
      xv[0] = a4.x; xv[1] = a4.y; xv[2] = a4.z; xv[3] = a4.w;
      xv[4] = b4.x; xv[5] = b4.y; xv[6] = b4.z; xv[7] = b4.w;
      xv[8] = xr[8]; xv[9] = xr[9];
      const float* wrow = &wsl[i * 192];
      float wv[3][4];
      *(float4*)wv[0] = *(const float4*)&wrow[(oy << 2)];
      *(float4*)wv[1] = *(const float4*)&wrow[64 + (oy << 2)];
      *(float4*)wv[2] = *(const float4*)&wrow[128 + (oy << 2)];
#pragma unroll
      for (int m = 0; m < 4; m++)
#pragma unroll
        for (int n = 0; n < 8; n++)
          acc[m][n] += wv[0][m] * xv[n] + wv[1][m] * xv[n + 1] + wv[2][m] * xv[n + 2];
    }
  }
#pragma unroll
  for (int m = 0; m < 4; m++) {
    int o = o0 + (oy << 2) + m;
    float bv = bias[o];
    size_t rowo = (((size_t)((b << 8) + o)) << 11) + t0 + (tx << 3);
#pragma unroll
    for (int n = 0; n < 8; n++) {
      float v = acc[m][n] + bv;
      if (src) v += src[rowo + n];
      out[rowo + n] = v;
    }
  }
}

__global__ __launch_bounds__(256) void conv1x1_k(const float* __restrict__ in, const float* __restrict__ wIO,
                                                 const float* __restrict__ bias, float* __restrict__ out,
                                                 int Kc, int O) {
  int b = blockIdx.x >> 3;
  int t0 = (blockIdx.x & 7) << 6;
  int o0 = blockIdx.y << 6;
  int tx = TID & 15, oy = TID >> 4;
  __shared__ float xs[32][64];
  __shared__ float wsd[32][64];
  float acc[4][4];
#pragma unroll
  for (int m = 0; m < 4; m++)
#pragma unroll
    for (int n = 0; n < 4; n++) acc[m][n] = 0.f;
  for (int ic0 = 0; ic0 < Kc; ic0 += 32) {
    __syncthreads();
    for (int idx = TID; idx < 2048; idx += 256) {
      int r = idx >> 6, c = idx & 63;
      xs[r][c] = in[((size_t)(b * Kc + ic0 + r) << 9) + t0 + c];
      wsd[r][c] = wIO[(ic0 + r) * O + o0 + c];
    }
    __syncthreads();
#pragma unroll 8
    for (int i = 0; i < 32; i++) {
      float4 xvv = *(const float4*)&xs[i][tx << 2];
      float4 wvv = *(const float4*)&wsd[i][oy << 2];
      float xv[4] = {xvv.x, xvv.y, xvv.z, xvv.w};
      float wv[4] = {wvv.x, wvv.y, wvv.z, wvv.w};
#pragma unroll
      for (int m = 0; m < 4; m++)
#pragma unroll
        for (int n = 0; n < 4; n++) acc[m][n] += wv[m] * xv[n];
    }
  }
#pragma unroll
  for (int m = 0; m < 4; m++) {
    int o = o0 + (oy << 2) + m;
    float bv = bias[o];
    size_t rowo = ((size_t)(b * O + o) << 9) + t0 + (tx << 2);
#pragma unroll
    for (int n = 0; n < 4; n++) out[rowo + n] = acc[m][n] + bv;
  }
}

__global__ __launch_bounds__(256) void conv_up_k(const float* __restrict__ in, const float* __restrict__ w,
                                                 const float* __restrict__ bias, float* __restrict__ out) {
  int b = blockIdx.x / 17;
  int s0 = (blockIdx.x % 17) << 5;
  int o0 = blockIdx.y << 6;
  int tx = TID & 15, oy = TID >> 4;
  __shared__ float ins[16][36];
  __shared__ float wsl[16 * 512];
  float acc[2][4][4];
#pragma unroll
  for (int j = 0; j < 2; j++)
#pragma unroll
    for (int m = 0; m < 4; m++)
#pragma unroll
      for (int r = 0; r < 4; r++) acc[j][m][r] = 0.f;
  for (int ic0 = 0; ic0 < 256; ic0 += 16) {
    __syncthreads();
    for (int idx = TID; idx < 16 * 34; idx += 256) {
      int r = idx / 34, c = idx % 34;
      int s = s0 - 1 + c;
      float v = 0.f;
      if (s >= 0 && s < 512) v = in[(((size_t)((b << 8) + ic0 + r)) << 9) + s];
      ins[r][c] = v;
    }
    for (int idx = TID; idx < 8192; idx += 256) {
      int rr = idx & 3;
      int o = (idx >> 2) & 63;
      int h = (idx >> 8) & 1;
      int i = idx >> 9;
      wsl[idx] = w[(((size_t)(ic0 + i)) << 11) + ((size_t)(o0 + o) << 3) + (h << 2) + rr];
    }
    __syncthreads();
#pragma unroll 2
    for (int i = 0; i < 16; i++) {
      float x0 = ins[i][2 * tx], x1 = ins[i][2 * tx + 1], x2 = ins[i][2 * tx + 2];
#pragma unroll
      for (int m = 0; m < 4; m++) {
        int om = (oy << 2) + m;
        float4 wa4 = *(const float4*)&wsl[(i << 9) + (om << 2)];
        float4 wb4 = *(const float4*)&wsl[(i << 9) + 256 + (om << 2)];
        float wa[4] = {wa4.x, wa4.y, wa4.z, wa4.w};
        float wb[4] = {wb4.x, wb4.y, wb4.z, wb4.w};
#pragma unroll
        for (int r = 0; r < 4; r++) {
          acc[0][m][r] += x1 * wa[r] + x0 * wb[r];
          acc[1][m][r] += x2 * wa[r] + x1 * wb[r];
        }
      }
    }
  }
#pragma unroll
  for (int j = 0; j < 2; j++) {
    int s1 = s0 + (tx << 1) + j;
#pragma unroll
    for (int m = 0; m < 4; m++) {
      int o = o0 + (oy << 2) + m;
      float bv = bias[o];
#pragma unroll
      for (int r = 0; r < 4; r++) {
        int t = (s1 << 2) + r - 2;
        if (t >= 0 && t < 2048) out[(((size_t)((b << 8) + o)) << 11) + t] = acc[j][m][r] + bv;
      }
    }
  }
}

__global__ __launch_bounds__(256) void conv_out_k(const float* __restrict__ in, const float* __restrict__ wP,
                                                  const float* __restrict__ bias, float* __restrict__ xhat) {
  int b = blockIdx.x >> 5;
  int t0 = (blockIdx.x & 31) << 6;
  int tx = TID & 63, oy = TID >> 6;
  __shared__ float ins[32][68];
  __shared__ float wsl[32 * 144];
  float acc[9];
#pragma unroll
  for (int m = 0; m < 9; m++) acc[m] = 0.f;
  for (int ic0 = 0; ic0 < 256; ic0 += 32) {
    __syncthreads();
    for (int idx = TID; idx < 32 * 66; idx += 256) {
      int r = idx / 66, c = idx % 66;
      int t = t0 - 1 + c;
      float v = 0.f;
      if (t >= 0 && t < 2048) v = in[(((size_t)((b << 8) + ic0 + r)) << 11) + t];
      ins[r][c] = v;
    }
    for (int idx = TID; idx < 32 * 144; idx += 256) {
      wsl[idx] = wP[ic0 * 144 + idx];
    }
    __syncthreads();
#pragma unroll 4
    for (int i = 0; i < 32; i++) {
      float x0 = ins[i][tx], x1 = ins[i][tx + 1], x2 = ins[i][tx + 2];
#pragma unroll
      for (int m = 0; m < 9; m++) {
        int o = oy * 9 + m;
        float4 wv = *(const float4*)&wsl[(i * 36 + o) << 2];
        acc[m] += wv.x * x0 + wv.y * x1 + wv.z * x2;
      }
    }
  }
  size_t orow = ((size_t)(b << 11) + t0 + tx) * 36;
#pragma unroll
  for (int m = 0; m < 9; m++) {
    int o = oy * 9 + m;
    xhat[orow + o] = acc[m] + bias[o];
  }
}

// ================= losses =================
__global__ __launch_bounds__(256) void loss_k(const float* __restrict__ x, const float* __restrict__ xh,
                                              const float* __restrict__ mask, float* __restrict__ scal) {
  float pos = 0.f, dir = 0.f, ms = 0.f;
  for (int n = blockIdx.x * blockDim.x + TID; n < 65536; n += gridDim.x * blockDim.x) {
    const float* xp = x + (size_t)n * 36;
    const float* hp = xh + (size_t)n * 36;
    float a[36], h[36];
#pragma unroll
    for (int d4 = 0; d4 < 36; d4 += 4) {
      *(float4*)&a[d4] = *(const float4*)&xp[d4];
      *(float4*)&h[d4] = *(const float4*)&hp[d4];
    }
#pragma unroll
    for (int d = 0; d < 36; d++) {
      if (d < 21 || (d >= 27 && d < 30)) {
        float df = h[d] - a[d];
        float ad = fabsf(df);
        pos += (ad < 1.f) ? 0.5f * df * df : ad - 0.5f;
      }
    }
    float mL = mask[2 * (size_t)n], mR = mask[2 * (size_t)n + 1];
    const int vb[4] = {21, 24, 30, 33};
    float mv[4] = {mL, mL, mR, mR};
#pragma unroll
    for (int v = 0; v < 4; v++) {
      int o = vb[v];
      float ax = a[o], ay = a[o + 1], az = a[o + 2];
      float hx = h[o], hy = h[o + 1], hz = h[o + 2];
      float an = sqrtf(ax * ax + ay * ay + az * az) + 1e-8f;
      float hn = sqrtf(hx * hx + hy * hy + hz * hz) + 1e-8f;
      float cs = (ax * hx + ay * hy + az * hz) / (an * hn);
      dir += (1.f - cs) * mv[v];
    }
    ms += 2.f * (mL + mR);
  }
  __shared__ float rp[256], rd[256], rm[256];
  rp[TID] = pos; rd[TID] = dir; rm[TID] = ms;
  __syncthreads();
  for (int st = 128; st > 0; st >>= 1) {
    if (TID < st) { rp[TID] += rp[TID + st]; rd[TID] += rd[TID + st]; rm[TID] += rm[TID + st]; }
    __syncthreads();
  }
  if (TID == 0) {
    atomicAdd(&scal[1], rp[0]);
    atomicAdd(&scal[2], rd[0]);
    atomicAdd(&scal[3], rm[0]);
  }
}

__global__ __launch_bounds__(256) void finalize_k(const float* __restrict__ counts, const float* __restrict__ scal,
                                                  float* __restrict__ tail) {
  __shared__ float red[256];
  float s = 0.f;
  for (int j = TID; j < 1024; j += 256) {
    float avg = counts[j] * (1.f / 16384.f);
    s += avg * logf(avg + 1e-10f);
  }
  red[TID] = s;
  __syncthreads();
  for (int st = 128; st > 0; st >>= 1) {
    if (TID < st) red[TID] += red[TID + st];
    __syncthreads();
  }
  if (TID == 0) {
    tail[0] = 1.25f * scal[0] * (1.f / 2097152.f);
    tail[1] = expf(-red[0]);
    tail[2] = scal[1] * (1.f / 65536.f);
    tail[3] = scal[2] / fmaxf(scal[3], 1.f);
  }
}

__global__ void codesf_k(const int* __restrict__ codes, float* __restrict__ o) {
  int n = blockIdx.x * blockDim.x + TID;
  if (n < 16384) o[n] = (float)codes[n];
}

// ================= host =================
extern "C" void kernel_launch(void* const* d_in, const int* in_sizes, int n_in,
                              void* d_out, int out_size, void* d_ws, size_t ws_size,
                              hipStream_t stream) {
  const float* x = (const float*)d_in[0];
  const float* mask = (const float*)d_in[1];
  const float* enc_in_w = (const float*)d_in[2];
  const float* enc_in_b = (const float*)d_in[3];
  const float* enc_gn1_g = (const float*)d_in[4];
  const float* enc_gn1_b = (const float*)d_in[5];
  const float* enc_c1_w = (const float*)d_in[6];
  const float* enc_c1_b = (const float*)d_in[7];
  const float* enc_gn2_g = (const float*)d_in[8];
  const float* enc_gn2_b = (const float*)d_in[9];
  const float* enc_c2_w = (const float*)d_in[10];
  const float* enc_c2_b = (const float*)d_in[11];
  const float* down_w = (const float*)d_in[12];
  const float* down_b = (const float*)d_in[13];
  const float* enc_out_w = (const float*)d_in[14];
  const float* enc_out_b = (const float*)d_in[15];
  const float* codebook = (const float*)d_in[16];
  const float* dec_in_w = (const float*)d_in[17];
  const float* dec_in_b = (const float*)d_in[18];
  const float* up_w = (const float*)d_in[19];
  const float* up_b = (const float*)d_in[20];
  const float* dec_gn1_g = (const float*)d_in[21];
  const float* dec_gn1_b = (const float*)d_in[22];
  const float* dec_c1_w = (const float*)d_in[23];
  const float* dec_c1_b = (const float*)d_in[24];
  const float* dec_gn2_g = (const float*)d_in[25];
  const float* dec_gn2_b = (const float*)d_in[26];
  const float* dec_c2_w = (const float*)d_in[27];
  const float* dec_c2_b = (const float*)d_in[28];
  const float* dec_out_w = (const float*)d_in[29];
  const float* dec_out_b = (const float*)d_in[30];

  char* W = (char*)d_ws;
  double* zE_d = (double*)(W + 0);                    // 16,777,216
  float* zQ = (float*)(W + 16777216);                 // 8,388,608
  int* codes = (int*)(W + 25165824);                  // 65,536
  float* counts = (float*)(W + 25231360);             // 4,096
  float* scal = (float*)(W + 25235456);               // 32
  float* csq = (float*)(W + 25235488);                // 4,096
  double* wd_c1 = (double*)(W + 25239584);            // 6,291,456
  double* wd_c2 = (double*)(W + 31531040);            // 6,291,456
  double* wd_enc_in = (double*)(W + 37822496);        // 221,184
  double* wd_down = (double*)(W + 38043680);          // 4,194,304
  double* wd_out = (double*)(W + 42237984);           // 262,144
  float* wf_dec_in = (float*)(W + 42500128);          // 131,072
  float* wf_dec_c1 = (float*)(W + 42631200);          // 3,145,728
  float* wf_dec_c2 = (float*)(W + 45776928);          // 3,145,728
  float* wf_dec_out = (float*)(W + 48922656);         // 147,456
  // big region @48MiB: encoder 3 x NB*256*2048 fp64 (33.5MB ea); decoder aliases (NBD fp32)
  double* e0 = (double*)(W + 50331648);
  double* e1 = (double*)(W + 50331648 + 33554432);
  double* e2 = (double*)(W + 50331648 + 2 * (size_t)33554432);
  float* f0 = (float*)(W + 50331648);
  float* f1 = (float*)(W + 50331648 + 33554432);
  float* f2 = (float*)(W + 50331648 + 2 * (size_t)33554432);
  float* dech = (float*)(W + 50331648 + 3 * (size_t)33554432);  // NBD*256*512 f32 = 8.4MB

  dim3 blk(256);
  zero_k<<<dim3(5), blk, 0, stream>>>(counts, 1032);
  perm_oik_iko_f64<<<dim3(1024), blk, 0, stream>>>(enc_c1_w, wd_c1, 4, 256, 256, 3);
  perm_oik_iko_f64<<<dim3(1024), blk, 0, stream>>>(enc_c2_w, wd_c2, 4, 256, 256, 3);
  perm_oik_iko_f64<<<dim3(128), blk, 0, stream>>>(enc_in_w, wd_enc_in, 1, 256, 36, 3);
  perm_oik_iko_f64<<<dim3(1024), blk, 0, stream>>>(down_w, wd_down, 1, 256, 256, 8);
  perm_oik_iko_f64<<<dim3(128), blk, 0, stream>>>(enc_out_w, wd_out, 1, 128, 256, 1);
  perm_oik_iko<<<dim3(128), blk, 0, stream>>>(dec_in_w, wf_dec_in, 1, 256, 128, 1);
  perm_oik_iko<<<dim3(1024), blk, 0, stream>>>(dec_c1_w, wf_dec_c1, 4, 256, 256, 3);
  perm_oik_iko<<<dim3(1024), blk, 0, stream>>>(dec_c2_w, wf_dec_c2, 4, 256, 256, 3);
  perm_decout<<<dim3(64), blk, 0, stream>>>(dec_out_w, wf_dec_out);
  csq_f32<<<dim3(4), blk, 0, stream>>>(codebook, csq);

  // ---- encoder (fp64), 4 chunks of NB=8 ----
  for (int ci = 0; ci < 4; ci++) {
    int b0 = ci * NB;
    conv_in_f64<<<dim3(NB * 32, 4), blk, 0, stream>>>(x + (size_t)b0 * 2048 * 36, wd_enc_in, enc_in_b, e0);
    for (int i = 0; i < 4; i++) {
      gn_silu_f64<<<dim3(NB * 8), blk, 0, stream>>>(e0, e1, enc_gn1_g + i * 256, enc_gn1_b + i * 256);
      conv3_f64<<<dim3(NB * 16, 4), blk, 0, stream>>>(e1, wd_c1 + i * 196608, enc_c1_b + i * 256, nullptr, e2);
      gn_silu_f64<<<dim3(NB * 8), blk, 0, stream>>>(e2, e1, enc_gn2_g + i * 256, enc_gn2_b + i * 256);
      conv3_f64<<<dim3(NB * 16, 4), blk, 0, stream>>>(e1, wd_c2 + i * 196608, enc_c2_b + i * 256, e0, e0);
    }
    conv_down_f64<<<dim3(NB * 8, 4), blk, 0, stream>>>(e0, wd_down, down_b, e1);
    conv1x1_f64<<<dim3(NB * 8, 2), blk, 0, stream>>>(e1, wd_out, enc_out_b, zE_d + (size_t)b0 * 128 * 512, 256, 128);
  }

  // ---- quantize (byte-identical kernel) ----
  nv_vq_f32<<<dim3(64), blk, 0, stream>>>(zE_d, codebook, csq, codes);
  count_k<<<dim3(64), blk, 0, stream>>>(codes, counts);
  gather_f64<<<dim3(512), blk, 0, stream>>>(codebook, codes, zE_d, zQ, &scal[0]);

  // ---- decoder (fp32), 2 chunks of NBD=16 ----
  float* xhat = (float*)d_out;
  for (int ci = 0; ci < 2; ci++) {
    int b0 = ci * NBD;
    conv1x1_k<<<dim3(NBD * 8, 4), blk, 0, stream>>>(zQ + (size_t)b0 * 128 * 512, wf_dec_in, dec_in_b, dech, 128, 256);
    conv_up_k<<<dim3(NBD * 17, 4), blk, 0, stream>>>(dech, up_w, up_b, f0);
    for (int i = 0; i < 4; i++) {
      gn_silu_k<<<dim3(NBD * 8), blk, 0, stream>>>(f0, f1, dec_gn1_g + i * 256, dec_gn1_b + i * 256);
      conv3_k<<<dim3(NBD * 16, 4), blk, 0, stream>>>(f1, wf_dec_c1 + i * 196608, dec_c1_b + i * 256, nullptr, f2);
      gn_silu_k<<<dim3(NBD * 8), blk, 0, stream>>>(f2, f1, dec_gn2_g + i * 256, dec_gn2_b + i * 256);
      conv3_k<<<dim3(NBD * 16, 4), blk, 0, stream>>>(f1, wf_dec_c2 + i * 196608, dec_c2_b + i * 256, f0, f0);
    }
    conv_out_k<<<dim3(NBD * 32), blk, 0, stream>>>(f0, wf_dec_out, dec_out_b, xhat + (size_t)b0 * 2048 * 36);
  }

  // ---- losses / scalars ----
  loss_k<<<dim3(256), blk, 0, stream>>>(x, xhat, mask, scal);
  finalize_k<<<dim3(1), blk, 0, stream>>>(counts, scal, (float*)d_out + 2375680);
  codesf_k<<<dim3(64), blk, 0, stream>>>(codes, (float*)d_out + 2359296);
}

// Round 6
// 16213.992 us; speedup vs baseline: 1.2412x; 1.2412x over previous
//
#include <hip/hip_runtime.h>
#include <cstddef>
#include <cstdint>

// VQ-VAE 1D forward. Encoder fp64 (z_e must be fp64-accurate; reference argmin follows
// fp32 dist formula zsq+csq-2zc with first-index ties — nv_vq_f32 keeps that exact
// per-point arithmetic sequence). Decoder fp32.
// R6: conv3 kernels reverted to r4 64x64 tiles (r5 128-tile caused 4/8-way LDS bank
// conflicts); GN split into full-grid part+apply; VQ unspilled (unrolled c-loops, 64-thr).
// d_out: x_hat (B,T,36) | codes as float (B,512) | [loss_vq, perplexity, loss_pos, loss_dir]

#define TID ((int)threadIdx.x)
#define NB 8    // encoder batches per chunk (fp64 buffers)
#define NBD 16  // decoder batches per chunk (fp32 buffers)

__device__ __forceinline__ float silu_f(float y) { return y / (1.f + expf(-y)); }

// ================= weight prep =================
__global__ void perm_oik_iko_f64(const float* __restrict__ src, double* __restrict__ dst,
                                 int R, int O, int I, int K) {
  int n = R * O * I * K;
  for (int idx = blockIdx.x * blockDim.x + TID; idx < n; idx += gridDim.x * blockDim.x) {
    int o = idx % O;
    int k = (idx / O) % K;
    int i = (idx / (O * K)) % I;
    int r = idx / (O * K * I);
    dst[idx] = (double)src[((r * O + o) * I + i) * K + k];
  }
}

__global__ void perm_oik_iko(const float* __restrict__ src, float* __restrict__ dst,
                             int R, int O, int I, int K) {
  int n = R * O * I * K;
  for (int idx = blockIdx.x * blockDim.x + TID; idx < n; idx += gridDim.x * blockDim.x) {
    int o = idx % O;
    int k = (idx / O) % K;
    int i = (idx / (O * K)) % I;
    int r = idx / (O * K * I);
    dst[idx] = src[((r * O + o) * I + i) * K + k];
  }
}

__global__ void perm_decout(const float* __restrict__ src, float* __restrict__ dst) {
  int n = 256 * 36 * 4;
  for (int idx = blockIdx.x * blockDim.x + TID; idx < n; idx += gridDim.x * blockDim.x) {
    int k = idx & 3;
    int o = (idx >> 2) % 36;
    int i = idx / 144;
    dst[idx] = (k < 3) ? src[(o * 256 + i) * 3 + k] : 0.f;
  }
}

__global__ void zero_k(float* p, int n) {
  int i = blockIdx.x * blockDim.x + TID;
  if (i < n) p[i] = 0.f;
}

// csq[j] = fp32 sequential sum of fl(c*c)
__global__ void csq_f32(const float* __restrict__ cb, float* __restrict__ csq) {
  int j = blockIdx.x * blockDim.x + TID;
  if (j < 1024) {
    float s = 0.f;
    for (int c = 0; c < 128; c++) { float v = cb[j * 128 + c]; s += v * v; }
    csq[j] = s;
  }
}

// ================= GroupNorm split: part (stats) + apply (normalize+silu) =========
// fp64: one (b,g) slice = 32ch x 2048 = 65536 doubles; 4 quarter-blocks each.
__global__ __launch_bounds__(256) void gn_part_f64(const double* __restrict__ in, double* __restrict__ part) {
  int bg = blockIdx.x >> 2, q = blockIdx.x & 3;
  const double2* src = (const double2*)(in + ((size_t)bg << 16) + ((size_t)q << 14));
  double s1 = 0., s2 = 0.;
  for (int f = TID; f < 8192; f += 256) {
    double2 v = src[f];
    s1 += v.x + v.y;
    s2 += v.x * v.x + v.y * v.y;
  }
  __shared__ double r1[256], r2[256];
  r1[TID] = s1; r2[TID] = s2;
  __syncthreads();
  for (int st = 128; st > 0; st >>= 1) {
    if (TID < st) { r1[TID] += r1[TID + st]; r2[TID] += r2[TID + st]; }
    __syncthreads();
  }
  if (TID == 0) { part[blockIdx.x * 2] = r1[0]; part[blockIdx.x * 2 + 1] = r2[0]; }
}

__global__ __launch_bounds__(256) void gn_apply_f64(const double* __restrict__ in, double* __restrict__ out,
                                                    const double* __restrict__ part,
                                                    const float* __restrict__ gamma, const float* __restrict__ beta) {
  int bg = blockIdx.x >> 2, q = blockIdx.x & 3;
  int g = bg & 7;
  const double* pp = part + (size_t)bg * 8;
  double s1 = pp[0] + pp[2] + pp[4] + pp[6];
  double s2 = pp[1] + pp[3] + pp[5] + pp[7];
  double mu = s1 * (1.0 / 65536.0);
  double var = s2 * (1.0 / 65536.0) - mu * mu;
  double rs = 1.0 / sqrt(var + 1e-5);
  size_t base = ((size_t)bg << 16) + ((size_t)q << 14);
  const double2* src = (const double2*)(in + base);
  double2* dst = (double2*)(out + base);
  for (int f = TID; f < 8192; f += 256) {
    int c = g * 32 + (((q << 14) + (f << 1)) >> 11);
    double a = rs * (double)gamma[c];
    double bb = (double)beta[c] - mu * a;
    double2 v = src[f];
    double y0 = v.x * a + bb, y1 = v.y * a + bb;
    double2 o;
    o.x = y0 / (1.0 + exp(-y0));
    o.y = y1 / (1.0 + exp(-y1));
    dst[f] = o;
  }
}

// fp32 versions (decoder): slice = 65536 floats, 4 quarters of 16384 (4096 float4)
__global__ __launch_bounds__(256) void gn_part_f32(const float* __restrict__ in, float* __restrict__ part) {
  int bg = blockIdx.x >> 2, q = blockIdx.x & 3;
  const float4* src = (const float4*)(in + ((size_t)bg << 16) + ((size_t)q << 14));
  float s1 = 0.f, s2 = 0.f;
  for (int f = TID; f < 4096; f += 256) {
    float4 v = src[f];
    s1 += v.x + v.y + v.z + v.w;
    s2 += v.x * v.x + v.y * v.y + v.z * v.z + v.w * v.w;
  }
  __shared__ float r1[256], r2[256];
  r1[TID] = s1; r2[TID] = s2;
  __syncthreads();
  for (int st = 128; st > 0; st >>= 1) {
    if (TID < st) { r1[TID] += r1[TID + st]; r2[TID] += r2[TID + st]; }
    __syncthreads();
  }
  if (TID == 0) { part[blockIdx.x * 2] = r1[0]; part[blockIdx.x * 2 + 1] = r2[0]; }
}

__global__ __launch_bounds__(256) void gn_apply_f32(const float* __restrict__ in, float* __restrict__ out,
                                                    const float* __restrict__ part,
                                                    const float* __restrict__ gamma, const float* __restrict__ beta) {
  int bg = blockIdx.x >> 2, q = blockIdx.x & 3;
  int g = bg & 7;
  const float* pp = part + (size_t)bg * 8;
  float s1 = pp[0] + pp[2] + pp[4] + pp[6];
  float s2 = pp[1] + pp[3] + pp[5] + pp[7];
  float mu = s1 * (1.f / 65536.f);
  float var = s2 * (1.f / 65536.f) - mu * mu;
  float rs = rsqrtf(var + 1e-5f);
  size_t base = ((size_t)bg << 16) + ((size_t)q << 14);
  const float4* src = (const float4*)(in + base);
  float4* dst = (float4*)(out + base);
  for (int f = TID; f < 4096; f += 256) {
    int c = g * 32 + (((q << 14) + (f << 2)) >> 11);
    float a = rs * gamma[c];
    float bb = beta[c] - mu * a;
    float4 v = src[f];
    float4 o;
    o.x = silu_f(v.x * a + bb);
    o.y = silu_f(v.y * a + bb);
    o.z = silu_f(v.z * a + bb);
    o.w = silu_f(v.w * a + bb);
    dst[f] = o;
  }
}

// ================= fp64 encoder convs (r4 shapes) =================
// input conv 36->256 fp64. grid=(NB*32,4)
__global__ __launch_bounds__(256) void conv_in_f64(const float* __restrict__ x, const double* __restrict__ wT,
                                                   const float* __restrict__ bias, double* __restrict__ out) {
  int b = blockIdx.x >> 5;
  int t0 = (blockIdx.x & 31) << 6;
  int o0 = blockIdx.y << 6;
  int tx = TID & 15, oy = TID >> 4;
  __shared__ double ins[36][68];
  __shared__ double wsl[36 * 192];
  for (int idx = TID; idx < 36 * 66; idx += 256) {
    int i = idx % 36, c = idx / 36;
    int t = t0 - 1 + c;
    double v = 0.;
    if (t >= 0 && t < 2048) v = (double)x[((size_t)(b * 2048 + t)) * 36 + i];
    ins[i][c] = v;
  }
  for (int idx = TID; idx < 36 * 192; idx += 256) {
    int o = idx & 63;
    int kk = (idx >> 6) % 3;
    int i = idx / 192;
    wsl[idx] = wT[(i * 3 + kk) * 256 + o0 + o];
  }
  __syncthreads();
  double acc[4][4];
#pragma unroll
  for (int m = 0; m < 4; m++)
#pragma unroll
    for (int n = 0; n < 4; n++) acc[m][n] = 0.;
  for (int i = 0; i < 36; i++) {
    double xv[6];
#pragma unroll
    for (int q = 0; q < 6; q++) xv[q] = ins[i][(tx << 2) + q];
    const double* wrow = &wsl[i * 192];
    double wv[3][4];
#pragma unroll
    for (int kk = 0; kk < 3; kk++)
#pragma unroll
      for (int m = 0; m < 4; m++) wv[kk][m] = wrow[kk * 64 + (oy << 2) + m];
#pragma unroll
    for (int m = 0; m < 4; m++)
#pragma unroll
      for (int n = 0; n < 4; n++)
        acc[m][n] += wv[0][m] * xv[n] + wv[1][m] * xv[n + 1] + wv[2][m] * xv[n + 2];
  }
  int obase = o0 + (oy << 2);
#pragma unroll
  for (int m = 0; m < 4; m++) {
    int o = obase + m;
    double bv = (double)bias[o];
    size_t rowo = (((size_t)((b << 8) + o)) << 11) + t0 + (tx << 2);
#pragma unroll
    for (int n = 0; n < 4; n++) out[rowo + n] = acc[m][n] + bv;
  }
}

// k=3 conv 256->256 fp64 (r4 64x64 tile). grid=(NB*32,4)
__global__ __launch_bounds__(256) void conv3_f64(const double* __restrict__ in, const double* __restrict__ wT,
                                                 const float* __restrict__ bias, const double* __restrict__ src,
                                                 double* __restrict__ out) {
  int b = blockIdx.x >> 5;
  int t0 = (blockIdx.x & 31) << 6;
  int o0 = blockIdx.y << 6;
  int tx = TID & 15, oy = TID >> 4;
  __shared__ double ins[16][68];
  __shared__ double wsl[16 * 192];
  double acc[4][4];
#pragma unroll
  for (int m = 0; m < 4; m++)
#pragma unroll
    for (int n = 0; n < 4; n++) acc[m][n] = 0.;
  for (int ic0 = 0; ic0 < 256; ic0 += 16) {
    __syncthreads();
    for (int idx = TID; idx < 16 * 66; idx += 256) {
      int r = idx / 66, c = idx % 66;
      int t = t0 - 1 + c;
      double v = 0.;
      if (t >= 0 && t < 2048) v = in[(((size_t)((b << 8) + ic0 + r)) << 11) + t];
      ins[r][c] = v;
    }
    for (int idx = TID; idx < 16 * 192; idx += 256) {
      int o = idx & 63;
      int kk = (idx >> 6) % 3;
      int i = idx / 192;
      wsl[idx] = wT[((ic0 + i) * 3 + kk) * 256 + o0 + o];
    }
    __syncthreads();
#pragma unroll 4
    for (int i = 0; i < 16; i++) {
      double xv[6];
#pragma unroll
      for (int q = 0; q < 6; q++) xv[q] = ins[i][(tx << 2) + q];
      const double* wrow = &wsl[i * 192];
      double wv[3][4];
#pragma unroll
      for (int kk = 0; kk < 3; kk++)
#pragma unroll
        for (int m = 0; m < 4; m++) wv[kk][m] = wrow[kk * 64 + (oy << 2) + m];
#pragma unroll
      for (int m = 0; m < 4; m++)
#pragma unroll
        for (int n = 0; n < 4; n++)
          acc[m][n] += wv[0][m] * xv[n] + wv[1][m] * xv[n + 1] + wv[2][m] * xv[n + 2];
    }
  }
  int obase = o0 + (oy << 2);
#pragma unroll
  for (int m = 0; m < 4; m++) {
    int o = obase + m;
    double bv = (double)bias[o];
    size_t rowo = (((size_t)((b << 8) + o)) << 11) + t0 + (tx << 2);
#pragma unroll
    for (int n = 0; n < 4; n++) {
      double v = acc[m][n] + bv;
      if (src) v += src[rowo + n];
      out[rowo + n] = v;
    }
  }
}

// down conv k=8 stride 4 fp64, Tout=512. grid=(NB*8,4)
__global__ __launch_bounds__(256) void conv_down_f64(const double* __restrict__ in, const double* __restrict__ wT,
                                                     const float* __restrict__ bias, double* __restrict__ out) {
  int b = blockIdx.x >> 3;
  int to0 = (blockIdx.x & 7) << 6;
  int o0 = blockIdx.y << 6;
  int tx = TID & 15, oy = TID >> 4;
  __shared__ double ins[8][264];
  __shared__ double wsl[8 * 512];
  double acc[4][4];
#pragma unroll
  for (int m = 0; m < 4; m++)
#pragma unroll
    for (int n = 0; n < 4; n++) acc[m][n] = 0.;
  for (int ic0 = 0; ic0 < 256; ic0 += 8) {
    __syncthreads();
    for (int idx = TID; idx < 8 * 260; idx += 256) {
      int r = idx / 260, c = idx % 260;
      int s = (to0 << 2) - 2 + c;
      double v = 0.;
      if (s >= 0 && s < 2048) v = in[(((size_t)((b << 8) + ic0 + r)) << 11) + s];
      ins[r][c] = v;
    }
    for (int idx = TID; idx < 8 * 512; idx += 256) {
      int o = idx & 63;
      int kk = (idx >> 6) & 7;
      int i = idx >> 9;
      wsl[idx] = wT[((ic0 + i) * 8 + kk) * 256 + o0 + o];
    }
    __syncthreads();
#pragma unroll
    for (int i = 0; i < 8; i++) {
      double xv[20];
#pragma unroll
      for (int q = 0; q < 20; q++) xv[q] = ins[i][(tx << 4) + q];
#pragma unroll
      for (int kk = 0; kk < 8; kk++) {
        double wv[4];
#pragma unroll
        for (int m = 0; m < 4; m++) wv[m] = wsl[(i << 9) + (kk << 6) + (oy << 2) + m];
#pragma unroll
        for (int n = 0; n < 4; n++) {
          double xval = xv[(n << 2) + kk];
#pragma unroll
          for (int m = 0; m < 4; m++) acc[m][n] += wv[m] * xval;
        }
      }
    }
  }
  int obase = o0 + (oy << 2);
#pragma unroll
  for (int m = 0; m < 4; m++) {
    int o = obase + m;
    double bv = (double)bias[o];
    size_t rowo = (((size_t)((b << 8) + o)) << 9) + to0 + (tx << 2);
#pragma unroll
    for (int n = 0; n < 4; n++) out[rowo + n] = acc[m][n] + bv;
  }
}

// 1x1 conv fp64, T=512. grid=(NB*8, O/64)
__global__ __launch_bounds__(256) void conv1x1_f64(const double* __restrict__ in, const double* __restrict__ wIO,
                                                   const float* __restrict__ bias, double* __restrict__ out,
                                                   int Kc, int O) {
  int b = blockIdx.x >> 3;
  int t0 = (blockIdx.x & 7) << 6;
  int o0 = blockIdx.y << 6;
  int tx = TID & 15, oy = TID >> 4;
  __shared__ double xs[32][64];
  __shared__ double wsd[32][64];
  double acc[4][4];
#pragma unroll
  for (int m = 0; m < 4; m++)
#pragma unroll
    for (int n = 0; n < 4; n++) acc[m][n] = 0.;
  for (int ic0 = 0; ic0 < Kc; ic0 += 32) {
    __syncthreads();
    for (int idx = TID; idx < 2048; idx += 256) {
      int r = idx >> 6, c = idx & 63;
      xs[r][c] = in[((size_t)(b * Kc + ic0 + r) << 9) + t0 + c];
      wsd[r][c] = wIO[(ic0 + r) * O + o0 + c];
    }
    __syncthreads();
#pragma unroll 8
    for (int i = 0; i < 32; i++) {
      double xv[4], wv[4];
#pragma unroll
      for (int q = 0; q < 4; q++) { xv[q] = xs[i][(tx << 2) + q]; wv[q] = wsd[i][(oy << 2) + q]; }
#pragma unroll
      for (int m = 0; m < 4; m++)
#pragma unroll
        for (int n = 0; n < 4; n++) acc[m][n] += wv[m] * xv[n];
    }
  }
#pragma unroll
  for (int m = 0; m < 4; m++) {
    int o = o0 + (oy << 2) + m;
    double bv = (double)bias[o];
    size_t rowo = ((size_t)(b * O + o) << 9) + t0 + (tx << 2);
#pragma unroll
    for (int n = 0; n < 4; n++) out[rowo + n] = acc[m][n] + bv;
  }
}

// ===== VQ: same per-point arithmetic sequence as the passing r4 kernel.
// Only parallel shape changed (64-thr blocks) + unrolled c-loops to keep z in VGPRs
// (r4 spilled z[128] to scratch: VGPR_Count=92, dur 1.16ms).
__global__ __launch_bounds__(64) void nv_vq_f32(const double* __restrict__ zE,
                                                const float* __restrict__ cb,
                                                const float* __restrict__ csq,
                                                int* __restrict__ codes) {
  int n = blockIdx.x * 64 + TID;  // 16384 points
  if (n >= 16384) return;
  int b = n >> 9, t = n & 511;
  const double* zp = zE + ((size_t)b * 128) * 512 + t;
  float z[128];
#pragma unroll
  for (int c = 0; c < 128; c++) z[c] = (float)zp[(size_t)c * 512];
  float zsq = 0.f;
#pragma unroll
  for (int c = 0; c < 128; c++) zsq += z[c] * z[c];
  float best = 3.4e38f;
  int bj = 0;
  for (int j = 0; j < 1024; j++) {
    const float* cr = cb + (size_t)j * 128;
    float zc = 0.f;
#pragma unroll
    for (int c = 0; c < 128; c++) zc += z[c] * cr[c];
    float A = zsq + csq[j];
    float B = 2.0f * zc;
    float d = A - B;
    if (d < best) { best = d; bj = j; }
  }
  codes[n] = bj;
}

// ================= VQ bookkeeping =================
__global__ void count_k(const int* __restrict__ codes, float* __restrict__ counts) {
  int n = blockIdx.x * blockDim.x + TID;
  if (n < 16384) atomicAdd(&counts[codes[n]], 1.f);
}

__global__ __launch_bounds__(256) void gather_f64(const float* __restrict__ cb, const int* __restrict__ codes,
                                                  const double* __restrict__ zE, float* __restrict__ zQ,
                                                  float* __restrict__ vqsum) {
  double part = 0.;
  const int total = 32 * 128 * 512;
  for (int idx = blockIdx.x * blockDim.x + TID; idx < total; idx += gridDim.x * blockDim.x) {
    int t = idx & 511;
    int c = (idx >> 9) & 127;
    int b = idx >> 16;
    int code = codes[(b << 9) + t];
    float q = cb[code * 128 + c];
    double d = (double)q - zE[idx];
    zQ[idx] = q;
    part += d * d;
  }
  __shared__ double red[256];
  red[TID] = part;
  __syncthreads();
  for (int st = 128; st > 0; st >>= 1) {
    if (TID < st) red[TID] += red[TID + st];
    __syncthreads();
  }
  if (TID == 0) atomicAdd(vqsum, (float)red[0]);
}

// ================= fp32 decoder convs (r4 shapes) =================
__global__ __launch_bounds__(256) void conv3_k(const float* __restrict__ in, const float* __restrict__ wT,
                                               const float* __restrict__ bias, const float* __restrict__ src,
                                               float* __restrict__ out) {
  int b = blockIdx.x >> 5;
  int t0 = (blockIdx.x & 31) << 6;
  int o0 = blockIdx.y << 6;
  int tx = TID & 15, oy = TID >> 4;
  __shared__ float ins[32][68];
  __shared__ float wsl[32 * 192];
  float acc[4][4];
#pragma unroll
  for (int m = 0; m < 4; m++)
#pragma unroll
    for (int n = 0; n < 4; n++) acc[m][n] = 0.f;
  for (int ic0 = 0; ic0 < 256; ic0 += 32) {
    __syncthreads();
    for (int idx = TID; idx < 32 * 66; idx += 256) {
      int r = idx / 66, c = idx % 66;
      int t = t0 - 1 + c;
      float v = 0.f;
      if (t >= 0 && t < 2048) v = in[(((size_t)((b << 8) + ic0 + r)) << 11) + t];
      ins[r][c] = v;
    }
    for (int idx = TID; idx < 32 * 192; idx += 256) {
      int o = idx & 63;
      int kk = (idx >> 6) % 3;
      int i = idx / 192;
      wsl[idx] = wT[((ic0 + i) * 3 + kk) * 256 + o0 + o];
    }
    __syncthreads();
#pragma unroll 4
    for (int i = 0; i < 32; i++) {
      float xv[6];
      float4 x4 = *(const float4*)&ins[i][tx << 2];
      xv[0] = x4.x; xv[1] = x4.y; xv[2] = x4.z; xv[3] = x4.w;
      xv[4] = ins[i][(tx << 2) + 4];
      xv[5] = ins[i][(tx << 2) + 5];
      const float* wrow = &wsl[i * 192];
      float wv[3][4];
      *(float4*)wv[0] = *(const float4*)&wrow[oy << 2];
      *(float4*)wv[1] = *(const float4*)&wrow[64 + (oy << 2)];
      *(float4*)wv[2] = *(const float4*)&wrow[128 + (oy << 2)];
#pragma unroll
      for (int m = 0; m < 4; m++)
#pragma unroll
        for (int n = 0; n < 4; n++)
          acc[m][n] += wv[0][m] * xv[n] + wv[1][m] * xv[n + 1] + wv[2][m] * xv[n + 2];
    }
  }
  int obase = o0 + (oy << 2);
#pragma unroll
  for (int m = 0; m < 4; m++) {
    int o = obase + m;
    float bv = bias[o];
    size_t rowo = (((size_t)((b << 8) + o)) << 11) + t0 + (tx << 2);
#pragma unroll
    for (int n = 0; n < 4; n++) {
      float v = acc[m][n] + bv;
      if (src) v += src[rowo + n];
      out[rowo + n] = v;
    }
  }
}

__global__ __launch_bounds__(256) void conv1x1_k(const float* __restrict__ in, const float* __restrict__ wIO,
                                                 const float* __restrict__ bias, float* __restrict__ out,
                                                 int Kc, int O) {
  int b = blockIdx.x >> 3;
  int t0 = (blockIdx.x & 7) << 6;
  int o0 = blockIdx.y << 6;
  int tx = TID & 15, oy = TID >> 4;
  __shared__ float xs[32][64];
  __shared__ float wsd[32][64];
  float acc[4][4];
#pragma unroll
  for (int m = 0; m < 4; m++)
#pragma unroll
    for (int n = 0; n < 4; n++) acc[m][n] = 0.f;
  for (int ic0 = 0; ic0 < Kc; ic0 += 32) {
    __syncthreads();
    for (int idx = TID; idx < 2048; idx += 256) {
      int r = idx >> 6, c = idx & 63;
      xs[r][c] = in[((size_t)(b * Kc + ic0 + r) << 9) + t0 + c];
      wsd[r][c] = wIO[(ic0 + r) * O + o0 + c];
    }
    __syncthreads();
#pragma unroll 8
    for (int i = 0; i < 32; i++) {
      float4 xvv = *(const float4*)&xs[i][tx << 2];
      float4 wvv = *(const float4*)&wsd[i][oy << 2];
      float xv[4] = {xvv.x, xvv.y, xvv.z, xvv.w};
      float wv[4] = {wvv.x, wvv.y, wvv.z, wvv.w};
#pragma unroll
      for (int m = 0; m < 4; m++)
#pragma unroll
        for (int n = 0; n < 4; n++) acc[m][n] += wv[m] * xv[n];
    }
  }
#pragma unroll
  for (int m = 0; m < 4; m++) {
    int o = o0 + (oy << 2) + m;
    float bv = bias[o];
    size_t rowo = ((size_t)(b * O + o) << 9) + t0 + (tx << 2);
#pragma unroll
    for (int n = 0; n < 4; n++) out[rowo + n] = acc[m][n] + bv;
  }
}

__global__ __launch_bounds__(256) void conv_up_k(const float* __restrict__ in, const float* __restrict__ w,
                                                 const float* __restrict__ bias, float* __restrict__ out) {
  int b = blockIdx.x / 17;
  int s0 = (blockIdx.x % 17) << 5;
  int o0 = blockIdx.y << 6;
  int tx = TID & 15, oy = TID >> 4;
  __shared__ float ins[16][36];
  __shared__ float wsl[16 * 512];
  float acc[2][4][4];
#pragma unroll
  for (int j = 0; j < 2; j++)
#pragma unroll
    for (int m = 0; m < 4; m++)
#pragma unroll
      for (int r = 0; r < 4; r++) acc[j][m][r] = 0.f;
  for (int ic0 = 0; ic0 < 256; ic0 += 16) {
    __syncthreads();
    for (int idx = TID; idx < 16 * 34; idx += 256) {
      int r = idx / 34, c = idx % 34;
      int s = s0 - 1 + c;
      float v = 0.f;
      if (s >= 0 && s < 512) v = in[(((size_t)((b << 8) + ic0 + r)) << 9) + s];
      ins[r][c] = v;
    }
    for (int idx = TID; idx < 8192; idx += 256) {
      int rr = idx & 3;
      int o = (idx >> 2) & 63;
      int h = (idx >> 8) & 1;
      int i = idx >> 9;
      wsl[idx] = w[(((size_t)(ic0 + i)) << 11) + ((size_t)(o0 + o) << 3) + (h << 2) + rr];
    }
    __syncthreads();
#pragma unroll 2
    for (int i = 0; i < 16; i++) {
      float x0 = ins[i][2 * tx], x1 = ins[i][2 * tx + 1], x2 = ins[i][2 * tx + 2];
#pragma unroll
      for (int m = 0; m < 4; m++) {
        int om = (oy << 2) + m;
        float4 wa4 = *(const float4*)&wsl[(i << 9) + (om << 2)];
        float4 wb4 = *(const float4*)&wsl[(i << 9) + 256 + (om << 2)];
        float wa[4] = {wa4.x, wa4.y, wa4.z, wa4.w};
        float wb[4] = {wb4.x, wb4.y, wb4.z, wb4.w};
#pragma unroll
        for (int r = 0; r < 4; r++) {
          acc[0][m][r] += x1 * wa[r] + x0 * wb[r];
          acc[1][m][r] += x2 * wa[r] + x1 * wb[r];
        }
      }
    }
  }
#pragma unroll
  for (int j = 0; j < 2; j++) {
    int s1 = s0 + (tx << 1) + j;
#pragma unroll
    for (int m = 0; m < 4; m++) {
      int o = o0 + (oy << 2) + m;
      float bv = bias[o];
#pragma unroll
      for (int r = 0; r < 4; r++) {
        int t = (s1 << 2) + r - 2;
        if (t >= 0 && t < 2048) out[(((size_t)((b << 8) + o)) << 11) + t] = acc[j][m][r] + bv;
      }
    }
  }
}

__global__ __launch_bounds__(256) void conv_out_k(const float* __restrict__ in, const float* __restrict__ wP,
                                                  const float* __restrict__ bias, float* __restrict__ xhat) {
  int b = blockIdx.x >> 5;
  int t0 = (blockIdx.x & 31) << 6;
  int tx = TID & 63, oy = TID >> 6;
  __shared__ float ins[32][68];
  __shared__ float wsl[32 * 144];
  float acc[9];
#pragma unroll
  for (int m = 0; m < 9; m++) acc[m] = 0.f;
  for (int ic0 = 0; ic0 < 256; ic0 += 32) {
    __syncthreads();
    for (int idx = TID; idx < 32 * 66; idx += 256) {
      int r = idx / 66, c = idx % 66;
      int t = t0 - 1 + c;
      float v = 0.f;
      if (t >= 0 && t < 2048) v = in[(((size_t)((b << 8) + ic0 + r)) << 11) + t];
      ins[r][c] = v;
    }
    for (int idx = TID; idx < 32 * 144; idx += 256) {
      wsl[idx] = wP[ic0 * 144 + idx];
    }
    __syncthreads();
#pragma unroll 4
    for (int i = 0; i < 32; i++) {
      float x0 = ins[i][tx], x1 = ins[i][tx + 1], x2 = ins[i][tx + 2];
#pragma unroll
      for (int m = 0; m < 9; m++) {
        int o = oy * 9 + m;
        float4 wv = *(const float4*)&wsl[(i * 36 + o) << 2];
        acc[m] += wv.x * x0 + wv.y * x1 + wv.z * x2;
      }
    }
  }
  size_t orow = ((size_t)(b << 11) + t0 + tx) * 36;
#pragma unroll
  for (int m = 0; m < 9; m++) {
    int o = oy * 9 + m;
    xhat[orow + o] = acc[m] + bias[o];
  }
}

// ================= losses =================
__global__ __launch_bounds__(256) void loss_k(const float* __restrict__ x, const float* __restrict__ xh,
                                              const float* __restrict__ mask, float* __restrict__ scal) {
  float pos = 0.f, dir = 0.f, ms = 0.f;
  for (int n = blockIdx.x * blockDim.x + TID; n < 65536; n += gridDim.x * blockDim.x) {
    const float* xp = x + (size_t)n * 36;
    const float* hp = xh + (size_t)n * 36;
    float a[36], h[36];
#pragma unroll
    for (int d4 = 0; d4 < 36; d4 += 4) {
      *(float4*)&a[d4] = *(const float4*)&xp[d4];
      *(float4*)&h[d4] = *(const float4*)&hp[d4];
    }
#pragma unroll
    for (int d = 0; d < 36; d++) {
      if (d < 21 || (d >= 27 && d < 30)) {
        float df = h[d] - a[d];
        float ad = fabsf(df);
        pos += (ad < 1.f) ? 0.5f * df * df : ad - 0.5f;
      }
    }
    float mL = mask[2 * (size_t)n], mR = mask[2 * (size_t)n + 1];
    const int vb[4] = {21, 24, 30, 33};
    float mv[4] = {mL, mL, mR, mR};
#pragma unroll
    for (int v = 0; v < 4; v++) {
      int o = vb[v];
      float ax = a[o], ay = a[o + 1], az = a[o + 2];
      float hx = h[o], hy = h[o + 1], hz = h[o + 2];
      float an = sqrtf(ax * ax + ay * ay + az * az) + 1e-8f;
      float hn = sqrtf(hx * hx + hy * hy + hz * hz) + 1e-8f;
      float cs = (ax * hx + ay * hy + az * hz) / (an * hn);
      dir += (1.f - cs) * mv[v];
    }
    ms += 2.f * (mL + mR);
  }
  __shared__ float rp[256], rd[256], rm[256];
  rp[TID] = pos; rd[TID] = dir; rm[TID] = ms;
  __syncthreads();
  for (int st = 128; st > 0; st >>= 1) {
    if (TID < st) { rp[TID] += rp[TID + st]; rd[TID] += rd[TID + st]; rm[TID] += rm[TID + st]; }
    __syncthreads();
  }
  if (TID == 0) {
    atomicAdd(&scal[1], rp[0]);
    atomicAdd(&scal[2], rd[0]);
    atomicAdd(&scal[3], rm[0]);
  }
}

__global__ __launch_bounds__(256) void finalize_k(const float* __restrict__ counts, const float* __restrict__ scal,
                                                  float* __restrict__ tail) {
  __shared__ float red[256];
  float s = 0.f;
  for (int j = TID; j < 1024; j += 256) {
    float avg = counts[j] * (1.f / 16384.f);
    s += avg * logf(avg + 1e-10f);
  }
  red[TID] = s;
  __syncthreads();
  for (int st = 128; st > 0; st >>= 1) {
    if (TID < st) red[TID] += red[TID + st];
    __syncthreads();
  }
  if (TID == 0) {
    tail[0] = 1.25f * scal[0] * (1.f / 2097152.f);
    tail[1] = expf(-red[0]);
    tail[2] = scal[1] * (1.f / 65536.f);
    tail[3] = scal[2] / fmaxf(scal[3], 1.f);
  }
}

__global__ void codesf_k(const int* __restrict__ codes, float* __restrict__ o) {
  int n = blockIdx.x * blockDim.x + TID;
  if (n < 16384) o[n] = (float)codes[n];
}

// ================= host =================
extern "C" void kernel_launch(void* const* d_in, const int* in_sizes, int n_in,
                              void* d_out, int out_size, void* d_ws, size_t ws_size,
                              hipStream_t stream) {
  const float* x = (const float*)d_in[0];
  const float* mask = (const float*)d_in[1];
  const float* enc_in_w = (const float*)d_in[2];
  const float* enc_in_b = (const float*)d_in[3];
  const float* enc_gn1_g = (const float*)d_in[4];
  const float* enc_gn1_b = (const float*)d_in[5];
  const float* enc_c1_w = (const float*)d_in[6];
  const float* enc_c1_b = (const float*)d_in[7];
  const float* enc_gn2_g = (const float*)d_in[8];
  const float* enc_gn2_b = (const float*)d_in[9];
  const float* enc_c2_w = (const float*)d_in[10];
  const float* enc_c2_b = (const float*)d_in[11];
  const float* down_w = (const float*)d_in[12];
  const float* down_b = (const float*)d_in[13];
  const float* enc_out_w = (const float*)d_in[14];
  const float* enc_out_b = (const float*)d_in[15];
  const float* codebook = (const float*)d_in[16];
  const float* dec_in_w = (const float*)d_in[17];
  const float* dec_in_b = (const float*)d_in[18];
  const float* up_w = (const float*)d_in[19];
  const float* up_b = (const float*)d_in[20];
  const float* dec_gn1_g = (const float*)d_in[21];
  const float* dec_gn1_b = (const float*)d_in[22];
  const float* dec_c1_w = (const float*)d_in[23];
  const float* dec_c1_b = (const float*)d_in[24];
  const float* dec_gn2_g = (const float*)d_in[25];
  const float* dec_gn2_b = (const float*)d_in[26];
  const float* dec_c2_w = (const float*)d_in[27];
  const float* dec_c2_b = (const float*)d_in[28];
  const float* dec_out_w = (const float*)d_in[29];
  const float* dec_out_b = (const float*)d_in[30];

  char* W = (char*)d_ws;
  double* zE_d = (double*)(W + 0);                    // 16,777,216
  float* zQ = (float*)(W + 16777216);                 // 8,388,608
  int* codes = (int*)(W + 25165824);                  // 65,536
  float* counts = (float*)(W + 25231360);             // 4,096
  float* scal = (float*)(W + 25235456);               // 32
  float* csq = (float*)(W + 25235488);                // 4,096
  double* part_d = (double*)(W + 25239584);           // 8,192 (up to 512 part pairs f64)
  float* part_f = (float*)(W + 25247776);             // 4,096
  double* wd_c1 = (double*)(W + 25251872);            // 6,291,456
  double* wd_c2 = (double*)(W + 31543328);            // 6,291,456
  double* wd_enc_in = (double*)(W + 37834784);        // 221,184
  double* wd_down = (double*)(W + 38055968);          // 4,194,304
  double* wd_out = (double*)(W + 42250272);           // 262,144
  float* wf_dec_in = (float*)(W + 42512416);          // 131,072
  float* wf_dec_c1 = (float*)(W + 42643488);          // 3,145,728
  float* wf_dec_c2 = (float*)(W + 45789216);          // 3,145,728
  float* wf_dec_out = (float*)(W + 48934944);         // 147,456
  // big region @48MiB: encoder 3 x NB*256*2048 fp64 (33.5MB ea); decoder aliases (NBD fp32)
  double* e0 = (double*)(W + 50331648);
  double* e1 = (double*)(W + 50331648 + 33554432);
  double* e2 = (double*)(W + 50331648 + 2 * (size_t)33554432);
  float* f0 = (float*)(W + 50331648);
  float* f1 = (float*)(W + 50331648 + 33554432);
  float* f2 = (float*)(W + 50331648 + 2 * (size_t)33554432);
  float* dech = (float*)(W + 50331648 + 3 * (size_t)33554432);  // NBD*256*512 f32 = 8.4MB

  dim3 blk(256);
  zero_k<<<dim3(5), blk, 0, stream>>>(counts, 1032);
  perm_oik_iko_f64<<<dim3(1024), blk, 0, stream>>>(enc_c1_w, wd_c1, 4, 256, 256, 3);
  perm_oik_iko_f64<<<dim3(1024), blk, 0, stream>>>(enc_c2_w, wd_c2, 4, 256, 256, 3);
  perm_oik_iko_f64<<<dim3(128), blk, 0, stream>>>(enc_in_w, wd_enc_in, 1, 256, 36, 3);
  perm_oik_iko_f64<<<dim3(1024), blk, 0, stream>>>(down_w, wd_down, 1, 256, 256, 8);
  perm_oik_iko_f64<<<dim3(128), blk, 0, stream>>>(enc_out_w, wd_out, 1, 128, 256, 1);
  perm_oik_iko<<<dim3(128), blk, 0, stream>>>(dec_in_w, wf_dec_in, 1, 256, 128, 1);
  perm_oik_iko<<<dim3(1024), blk, 0, stream>>>(dec_c1_w, wf_dec_c1, 4, 256, 256, 3);
  perm_oik_iko<<<dim3(1024), blk, 0, stream>>>(dec_c2_w, wf_dec_c2, 4, 256, 256, 3);
  perm_decout<<<dim3(64), blk, 0, stream>>>(dec_out_w, wf_dec_out);
  csq_f32<<<dim3(4), blk, 0, stream>>>(codebook, csq);

  // ---- encoder (fp64), 4 chunks of NB=8 ----
  const int GNE = NB * 8 * 4;  // 256 blocks
  for (int ci = 0; ci < 4; ci++) {
    int b0 = ci * NB;
    conv_in_f64<<<dim3(NB * 32, 4), blk, 0, stream>>>(x + (size_t)b0 * 2048 * 36, wd_enc_in, enc_in_b, e0);
    for (int i = 0; i < 4; i++) {
      gn_part_f64<<<dim3(GNE), blk, 0, stream>>>(e0, part_d);
      gn_apply_f64<<<dim3(GNE), blk, 0, stream>>>(e0, e1, part_d, enc_gn1_g + i * 256, enc_gn1_b + i * 256);
      conv3_f64<<<dim3(NB * 32, 4), blk, 0, stream>>>(e1, wd_c1 + i * 196608, enc_c1_b + i * 256, nullptr, e2);
      gn_part_f64<<<dim3(GNE), blk, 0, stream>>>(e2, part_d);
      gn_apply_f64<<<dim3(GNE), blk, 0, stream>>>(e2, e2, part_d, enc_gn2_g + i * 256, enc_gn2_b + i * 256);
      conv3_f64<<<dim3(NB * 32, 4), blk, 0, stream>>>(e2, wd_c2 + i * 196608, enc_c2_b + i * 256, e0, e0);
    }
    conv_down_f64<<<dim3(NB * 8, 4), blk, 0, stream>>>(e0, wd_down, down_b, e1);
    conv1x1_f64<<<dim3(NB * 8, 2), blk, 0, stream>>>(e1, wd_out, enc_out_b, zE_d + (size_t)b0 * 128 * 512, 256, 128);
  }

  // ---- quantize ----
  nv_vq_f32<<<dim3(256), dim3(64), 0, stream>>>(zE_d, codebook, csq, codes);
  count_k<<<dim3(64), blk, 0, stream>>>(codes, counts);
  gather_f64<<<dim3(512), blk, 0, stream>>>(codebook, codes, zE_d, zQ, &scal[0]);

  // ---- decoder (fp32), 2 chunks of NBD=16 ----
  const int GND = NBD * 8 * 4;  // 512 blocks
  float* xhat = (float*)d_out;
  for (int ci = 0; ci < 2; ci++) {
    int b0 = ci * NBD;
    conv1x1_k<<<dim3(NBD * 8, 4), blk, 0, stream>>>(zQ + (size_t)b0 * 128 * 512, wf_dec_in, dec_in_b, dech, 128, 256);
    conv_up_k<<<dim3(NBD * 17, 4), blk, 0, stream>>>(dech, up_w, up_b, f0);
    for (int i = 0; i < 4; i++) {
      gn_part_f32<<<dim3(GND), blk, 0, stream>>>(f0, part_f);
      gn_apply_f32<<<dim3(GND), blk, 0, stream>>>(f0, f1, part_f, dec_gn1_g + i * 256, dec_gn1_b + i * 256);
      conv3_k<<<dim3(NBD * 32, 4), blk, 0, stream>>>(f1, wf_dec_c1 + i * 196608, dec_c1_b + i * 256, nullptr, f2);
      gn_part_f32<<<dim3(GND), blk, 0, stream>>>(f2, part_f);
      gn_apply_f32<<<dim3(GND), blk, 0, stream>>>(f2, f2, part_f, dec_gn2_g + i * 256, dec_gn2_b + i * 256);
      conv3_k<<<dim3(NBD * 32, 4), blk, 0, stream>>>(f2, wf_dec_c2 + i * 196608, dec_c2_b + i * 256, f0, f0);
    }
    conv_out_k<<<dim3(NBD * 32), blk, 0, stream>>>(f0, wf_dec_out, dec_out_b, xhat + (size_t)b0 * 2048 * 36);
  }

  // ---- losses / scalars ----
  loss_k<<<dim3(256), blk, 0, stream>>>(x, xhat, mask, scal);
  finalize_k<<<dim3(1), blk, 0, stream>>>(counts, scal, (float*)d_out + 2375680);
  codesf_k<<<dim3(64), blk, 0, stream>>>(codes, (float*)d_out + 2359296);
}

// Round 7
// 10323.817 us; speedup vs baseline: 1.9494x; 1.5705x over previous
//
#include <hip/hip_runtime.h>
#include <cstddef>
#include <cstdint>

// VQ-VAE 1D forward — full fp32 pipeline.
// Codes: reference argmin follows fp32 dist = fl(zsq+csq) - fl(2*zc), first-index ties.
// vq_tiled preserves the exact per-(point,code) sequential fp32 FMA chain over c=0..127
// (same source expressions as the r4-passing kernel => same contraction/rounding).
// fp32 encoder justified: r0(fp32) vs r1/r3(fp64) encoders gave bit-identical argmin sets.
// d_out: x_hat (B,T,36) | codes as float (B,512) | [loss_vq, perplexity, loss_pos, loss_dir]

#define TID ((int)threadIdx.x)
#define NB 16  // batches per chunk (both phases)

__device__ __forceinline__ float silu_f(float y) { return y / (1.f + expf(-y)); }

// ================= weight prep =================
__global__ void perm_oik_iko(const float* __restrict__ src, float* __restrict__ dst,
                             int R, int O, int I, int K) {
  int n = R * O * I * K;
  for (int idx = blockIdx.x * blockDim.x + TID; idx < n; idx += gridDim.x * blockDim.x) {
    int o = idx % O;
    int k = (idx / O) % K;
    int i = (idx / (O * K)) % I;
    int r = idx / (O * K * I);
    dst[idx] = src[((r * O + o) * I + i) * K + k];
  }
}

__global__ void perm_decout(const float* __restrict__ src, float* __restrict__ dst) {
  int n = 256 * 36 * 4;
  for (int idx = blockIdx.x * blockDim.x + TID; idx < n; idx += gridDim.x * blockDim.x) {
    int k = idx & 3;
    int o = (idx >> 2) % 36;
    int i = idx / 144;
    dst[idx] = (k < 3) ? src[(o * 256 + i) * 3 + k] : 0.f;
  }
}

__global__ void zero_k(float* p, int n) {
  int i = blockIdx.x * blockDim.x + TID;
  if (i < n) p[i] = 0.f;
}

// csq[j] = fp32 sequential sum of fl(c*c)
__global__ void csq_f32(const float* __restrict__ cb, float* __restrict__ csq) {
  int j = blockIdx.x * blockDim.x + TID;
  if (j < 1024) {
    float s = 0.f;
    for (int c = 0; c < 128; c++) { float v = cb[j * 128 + c]; s += v * v; }
    csq[j] = s;
  }
}

// ================= GroupNorm split (fp32) =================
__global__ __launch_bounds__(256) void gn_part_f32(const float* __restrict__ in, float* __restrict__ part) {
  int bg = blockIdx.x >> 2, q = blockIdx.x & 3;
  const float4* src = (const float4*)(in + ((size_t)bg << 16) + ((size_t)q << 14));
  float s1 = 0.f, s2 = 0.f;
  for (int f = TID; f < 4096; f += 256) {
    float4 v = src[f];
    s1 += v.x + v.y + v.z + v.w;
    s2 += v.x * v.x + v.y * v.y + v.z * v.z + v.w * v.w;
  }
  __shared__ float r1[256], r2[256];
  r1[TID] = s1; r2[TID] = s2;
  __syncthreads();
  for (int st = 128; st > 0; st >>= 1) {
    if (TID < st) { r1[TID] += r1[TID + st]; r2[TID] += r2[TID + st]; }
    __syncthreads();
  }
  if (TID == 0) { part[blockIdx.x * 2] = r1[0]; part[blockIdx.x * 2 + 1] = r2[0]; }
}

__global__ __launch_bounds__(256) void gn_apply_f32(const float* __restrict__ in, float* __restrict__ out,
                                                    const float* __restrict__ part,
                                                    const float* __restrict__ gamma, const float* __restrict__ beta) {
  int bg = blockIdx.x >> 2, q = blockIdx.x & 3;
  int g = bg & 7;
  const float* pp = part + (size_t)bg * 8;
  float s1 = pp[0] + pp[2] + pp[4] + pp[6];
  float s2 = pp[1] + pp[3] + pp[5] + pp[7];
  float mu = s1 * (1.f / 65536.f);
  float var = s2 * (1.f / 65536.f) - mu * mu;
  float rs = rsqrtf(var + 1e-5f);
  size_t base = ((size_t)bg << 16) + ((size_t)q << 14);
  const float4* src = (const float4*)(in + base);
  float4* dst = (float4*)(out + base);
  for (int f = TID; f < 4096; f += 256) {
    int c = g * 32 + (((q << 14) + (f << 2)) >> 11);
    float a = rs * gamma[c];
    float bb = beta[c] - mu * a;
    float4 v = src[f];
    float4 o;
    o.x = silu_f(v.x * a + bb);
    o.y = silu_f(v.y * a + bb);
    o.z = silu_f(v.z * a + bb);
    o.w = silu_f(v.w * a + bb);
    dst[f] = o;
  }
}

// ================= fp32 convs =================
// input conv 36->256, k=3. grid=(NB*32,4)
__global__ __launch_bounds__(256) void conv_in_k(const float* __restrict__ x, const float* __restrict__ wT,
                                                 const float* __restrict__ bias, float* __restrict__ out) {
  int b = blockIdx.x >> 5;
  int t0 = (blockIdx.x & 31) << 6;
  int o0 = blockIdx.y << 6;
  int tx = TID & 15, oy = TID >> 4;
  __shared__ float ins[36][68];
  __shared__ float wsl[36 * 192];
  for (int idx = TID; idx < 36 * 66; idx += 256) {
    int i = idx % 36, c = idx / 36;
    int t = t0 - 1 + c;
    float v = 0.f;
    if (t >= 0 && t < 2048) v = x[((size_t)(b * 2048 + t)) * 36 + i];
    ins[i][c] = v;
  }
  for (int idx = TID; idx < 36 * 192; idx += 256) {
    int o = idx & 63;
    int kk = (idx >> 6) % 3;
    int i = idx / 192;
    wsl[idx] = wT[(i * 3 + kk) * 256 + o0 + o];
  }
  __syncthreads();
  float acc[4][4];
#pragma unroll
  for (int m = 0; m < 4; m++)
#pragma unroll
    for (int n = 0; n < 4; n++) acc[m][n] = 0.f;
  for (int i = 0; i < 36; i++) {
    float xv[6];
    float4 x4 = *(const float4*)&ins[i][tx << 2];
    xv[0] = x4.x; xv[1] = x4.y; xv[2] = x4.z; xv[3] = x4.w;
    xv[4] = ins[i][(tx << 2) + 4];
    xv[5] = ins[i][(tx << 2) + 5];
    const float* wrow = &wsl[i * 192];
    float wv[3][4];
    *(float4*)wv[0] = *(const float4*)&wrow[oy << 2];
    *(float4*)wv[1] = *(const float4*)&wrow[64 + (oy << 2)];
    *(float4*)wv[2] = *(const float4*)&wrow[128 + (oy << 2)];
#pragma unroll
    for (int m = 0; m < 4; m++)
#pragma unroll
      for (int n = 0; n < 4; n++)
        acc[m][n] += wv[0][m] * xv[n] + wv[1][m] * xv[n + 1] + wv[2][m] * xv[n + 2];
  }
  int obase = o0 + (oy << 2);
#pragma unroll
  for (int m = 0; m < 4; m++) {
    int o = obase + m;
    float bv = bias[o];
    size_t rowo = (((size_t)((b << 8) + o)) << 11) + t0 + (tx << 2);
#pragma unroll
    for (int n = 0; n < 4; n++) out[rowo + n] = acc[m][n] + bv;
  }
}

// k=3 conv 256->256, 64x64 tile, optional residual. grid=(NB*32,4)
__global__ __launch_bounds__(256) void conv3_k(const float* __restrict__ in, const float* __restrict__ wT,
                                               const float* __restrict__ bias, const float* __restrict__ src,
                                               float* __restrict__ out) {
  int b = blockIdx.x >> 5;
  int t0 = (blockIdx.x & 31) << 6;
  int o0 = blockIdx.y << 6;
  int tx = TID & 15, oy = TID >> 4;
  __shared__ float ins[32][68];
  __shared__ float wsl[32 * 192];
  float acc[4][4];
#pragma unroll
  for (int m = 0; m < 4; m++)
#pragma unroll
    for (int n = 0; n < 4; n++) acc[m][n] = 0.f;
  for (int ic0 = 0; ic0 < 256; ic0 += 32) {
    __syncthreads();
    for (int idx = TID; idx < 32 * 66; idx += 256) {
      int r = idx / 66, c = idx % 66;
      int t = t0 - 1 + c;
      float v = 0.f;
      if (t >= 0 && t < 2048) v = in[(((size_t)((b << 8) + ic0 + r)) << 11) + t];
      ins[r][c] = v;
    }
    for (int idx = TID; idx < 32 * 192; idx += 256) {
      int o = idx & 63;
      int kk = (idx >> 6) % 3;
      int i = idx / 192;
      wsl[idx] = wT[((ic0 + i) * 3 + kk) * 256 + o0 + o];
    }
    __syncthreads();
#pragma unroll 4
    for (int i = 0; i < 32; i++) {
      float xv[6];
      float4 x4 = *(const float4*)&ins[i][tx << 2];
      xv[0] = x4.x; xv[1] = x4.y; xv[2] = x4.z; xv[3] = x4.w;
      xv[4] = ins[i][(tx << 2) + 4];
      xv[5] = ins[i][(tx << 2) + 5];
      const float* wrow = &wsl[i * 192];
      float wv[3][4];
      *(float4*)wv[0] = *(const float4*)&wrow[oy << 2];
      *(float4*)wv[1] = *(const float4*)&wrow[64 + (oy << 2)];
      *(float4*)wv[2] = *(const float4*)&wrow[128 + (oy << 2)];
#pragma unroll
      for (int m = 0; m < 4; m++)
#pragma unroll
        for (int n = 0; n < 4; n++)
          acc[m][n] += wv[0][m] * xv[n] + wv[1][m] * xv[n + 1] + wv[2][m] * xv[n + 2];
    }
  }
  int obase = o0 + (oy << 2);
#pragma unroll
  for (int m = 0; m < 4; m++) {
    int o = obase + m;
    float bv = bias[o];
    size_t rowo = (((size_t)((b << 8) + o)) << 11) + t0 + (tx << 2);
#pragma unroll
    for (int n = 0; n < 4; n++) {
      float v = acc[m][n] + bv;
      if (src) v += src[rowo + n];
      out[rowo + n] = v;
    }
  }
}

// down conv k=8 stride 4, Tout=512. grid=(NB*8,4)
__global__ __launch_bounds__(256) void conv_down_k(const float* __restrict__ in, const float* __restrict__ wT,
                                                   const float* __restrict__ bias, float* __restrict__ out) {
  int b = blockIdx.x >> 3;
  int to0 = (blockIdx.x & 7) << 6;
  int o0 = blockIdx.y << 6;
  int tx = TID & 15, oy = TID >> 4;
  __shared__ float ins[16][264];
  __shared__ float wsl[16 * 512];
  float acc[4][4];
#pragma unroll
  for (int m = 0; m < 4; m++)
#pragma unroll
    for (int n = 0; n < 4; n++) acc[m][n] = 0.f;
  for (int ic0 = 0; ic0 < 256; ic0 += 16) {
    __syncthreads();
    for (int idx = TID; idx < 16 * 260; idx += 256) {
      int r = idx / 260, c = idx % 260;
      int s = (to0 << 2) - 2 + c;
      float v = 0.f;
      if (s >= 0 && s < 2048) v = in[(((size_t)((b << 8) + ic0 + r)) << 11) + s];
      ins[r][c] = v;
    }
    for (int idx = TID; idx < 16 * 512; idx += 256) {
      int o = idx & 63;
      int kk = (idx >> 6) & 7;
      int i = idx >> 9;
      wsl[idx] = wT[((ic0 + i) * 8 + kk) * 256 + o0 + o];
    }
    __syncthreads();
#pragma unroll 2
    for (int i = 0; i < 16; i++) {
      float xv[20];
#pragma unroll
      for (int q = 0; q < 5; q++) *(float4*)&xv[q * 4] = *(const float4*)&ins[i][(tx << 4) + (q << 2)];
      float wv[8][4];
#pragma unroll
      for (int kk = 0; kk < 8; kk++) *(float4*)wv[kk] = *(const float4*)&wsl[(i << 9) + (kk << 6) + (oy << 2)];
#pragma unroll
      for (int n = 0; n < 4; n++)
#pragma unroll
        for (int kk = 0; kk < 8; kk++) {
          float xval = xv[(n << 2) + kk];
#pragma unroll
          for (int m = 0; m < 4; m++) acc[m][n] += wv[kk][m] * xval;
        }
    }
  }
  int obase = o0 + (oy << 2);
#pragma unroll
  for (int m = 0; m < 4; m++) {
    int o = obase + m;
    float bv = bias[o];
    size_t rowo = (((size_t)((b << 8) + o)) << 9) + to0 + (tx << 2);
#pragma unroll
    for (int n = 0; n < 4; n++) out[rowo + n] = acc[m][n] + bv;
  }
}

// 1x1 conv, T=512. grid=(NB*8, O/64)
__global__ __launch_bounds__(256) void conv1x1_k(const float* __restrict__ in, const float* __restrict__ wIO,
                                                 const float* __restrict__ bias, float* __restrict__ out,
                                                 int Kc, int O) {
  int b = blockIdx.x >> 3;
  int t0 = (blockIdx.x & 7) << 6;
  int o0 = blockIdx.y << 6;
  int tx = TID & 15, oy = TID >> 4;
  __shared__ float xs[32][64];
  __shared__ float wsd[32][64];
  float acc[4][4];
#pragma unroll
  for (int m = 0; m < 4; m++)
#pragma unroll
    for (int n = 0; n < 4; n++) acc[m][n] = 0.f;
  for (int ic0 = 0; ic0 < Kc; ic0 += 32) {
    __syncthreads();
    for (int idx = TID; idx < 2048; idx += 256) {
      int r = idx >> 6, c = idx & 63;
      xs[r][c] = in[((size_t)(b * Kc + ic0 + r) << 9) + t0 + c];
      wsd[r][c] = wIO[(ic0 + r) * O + o0 + c];
    }
    __syncthreads();
#pragma unroll 8
    for (int i = 0; i < 32; i++) {
      float4 xvv = *(const float4*)&xs[i][tx << 2];
      float4 wvv = *(const float4*)&wsd[i][oy << 2];
      float xv[4] = {xvv.x, xvv.y, xvv.z, xvv.w};
      float wv[4] = {wvv.x, wvv.y, wvv.z, wvv.w};
#pragma unroll
      for (int m = 0; m < 4; m++)
#pragma unroll
        for (int n = 0; n < 4; n++) acc[m][n] += wv[m] * xv[n];
    }
  }
#pragma unroll
  for (int m = 0; m < 4; m++) {
    int o = o0 + (oy << 2) + m;
    float bv = bias[o];
    size_t rowo = ((size_t)(b * O + o) << 9) + t0 + (tx << 2);
#pragma unroll
    for (int n = 0; n < 4; n++) out[rowo + n] = acc[m][n] + bv;
  }
}

// ===== VQ tiled: preserves the r4-passing per-(point,code) fp32 chain semantics =====
// dist = fl(zsq + csq[j]) - fl(2*zc); zc,zsq = sequential fp32 FMA chains over c=0..127;
// argmin = first-min over ascending j (per-thread ascending + cross-thread j tie-break).
__global__ __launch_bounds__(256) void vq_tiled(const float* __restrict__ zE,
                                                const float* __restrict__ cb,
                                                const float* __restrict__ csq,
                                                int* __restrict__ codes) {
  int b = blockIdx.x >> 3;
  int t0 = (blockIdx.x & 7) << 6;
  int cq = TID & 15, pq = TID >> 4;
  __shared__ float Zs[128][66];
  __shared__ float Cs[64][129];
  __shared__ float zsqs[64];
  __shared__ float bd[64][17];
  __shared__ int bix[64][17];
  for (int idx = TID; idx < 128 * 64; idx += 256) {
    int c = idx >> 6, p = idx & 63;
    Zs[c][p] = zE[((size_t)(b * 128 + c) << 9) + t0 + p];
  }
  __syncthreads();
  if (TID < 64) {
    float s = 0.f;
    for (int c = 0; c < 128; c++) { float v = Zs[c][TID]; s += v * v; }
    zsqs[TID] = s;
  }
  float best[4];
  int bidx[4];
#pragma unroll
  for (int n = 0; n < 4; n++) { best[n] = 3.4e38f; bidx[n] = 0; }
  const int j0 = cq << 2;
  for (int cg = 0; cg < 16; cg++) {
    __syncthreads();
    for (int idx = TID; idx < 64 * 128; idx += 256) {
      int j = idx >> 7, c = idx & 127;
      Cs[j][c] = cb[((cg << 6) + j) * 128 + c];
    }
    __syncthreads();
    float acc[4][4];
#pragma unroll
    for (int u = 0; u < 4; u++)
#pragma unroll
      for (int n = 0; n < 4; n++) acc[u][n] = 0.f;
    for (int c = 0; c < 128; c++) {
      float4 zv4 = *(const float4*)&Zs[c][pq << 2];
      float zv[4] = {zv4.x, zv4.y, zv4.z, zv4.w};
      float cv[4];
#pragma unroll
      for (int u = 0; u < 4; u++) cv[u] = Cs[j0 + u][c];
#pragma unroll
      for (int u = 0; u < 4; u++)
#pragma unroll
        for (int n = 0; n < 4; n++) acc[u][n] += zv[n] * cv[u];
    }
#pragma unroll
    for (int u = 0; u < 4; u++) {
      int code = (cg << 6) + j0 + u;
      float cs_ = csq[code];
#pragma unroll
      for (int n = 0; n < 4; n++) {
        float A = zsqs[(pq << 2) + n] + cs_;
        float B = 2.0f * acc[u][n];
        float d = A - B;
        if (d < best[n]) { best[n] = d; bidx[n] = code; }
      }
    }
  }
  __syncthreads();
#pragma unroll
  for (int n = 0; n < 4; n++) { bd[(pq << 2) + n][cq] = best[n]; bix[(pq << 2) + n][cq] = bidx[n]; }
  __syncthreads();
  if (TID < 64) {
    float bb = bd[TID][0];
    int bj = bix[TID][0];
    for (int q = 1; q < 16; q++) {
      float d = bd[TID][q];
      int j = bix[TID][q];
      if (d < bb || (d == bb && j < bj)) { bb = d; bj = j; }
    }
    codes[(b << 9) + t0 + TID] = bj;
  }
}

// ================= VQ bookkeeping =================
__global__ void count_k(const int* __restrict__ codes, float* __restrict__ counts) {
  int n = blockIdx.x * blockDim.x + TID;
  if (n < 16384) atomicAdd(&counts[codes[n]], 1.f);
}

__global__ __launch_bounds__(256) void gather_k(const float* __restrict__ cb, const int* __restrict__ codes,
                                                const float* __restrict__ zE, float* __restrict__ zQ,
                                                float* __restrict__ vqsum) {
  double part = 0.;
  const int total = 32 * 128 * 512;
  for (int idx = blockIdx.x * blockDim.x + TID; idx < total; idx += gridDim.x * blockDim.x) {
    int t = idx & 511;
    int c = (idx >> 9) & 127;
    int b = idx >> 16;
    int code = codes[(b << 9) + t];
    float q = cb[code * 128 + c];
    double d = (double)q - (double)zE[idx];
    zQ[idx] = q;
    part += d * d;
  }
  __shared__ double red[256];
  red[TID] = part;
  __syncthreads();
  for (int st = 128; st > 0; st >>= 1) {
    if (TID < st) red[TID] += red[TID + st];
    __syncthreads();
  }
  if (TID == 0) atomicAdd(vqsum, (float)red[0]);
}

// ================= decoder-only convs =================
__global__ __launch_bounds__(256) void conv_up_k(const float* __restrict__ in, const float* __restrict__ w,
                                                 const float* __restrict__ bias, float* __restrict__ out) {
  int b = blockIdx.x / 17;
  int s0 = (blockIdx.x % 17) << 5;
  int o0 = blockIdx.y << 6;
  int tx = TID & 15, oy = TID >> 4;
  __shared__ float ins[16][36];
  __shared__ float wsl[16 * 512];
  float acc[2][4][4];
#pragma unroll
  for (int j = 0; j < 2; j++)
#pragma unroll
    for (int m = 0; m < 4; m++)
#pragma unroll
      for (int r = 0; r < 4; r++) acc[j][m][r] = 0.f;
  for (int ic0 = 0; ic0 < 256; ic0 += 16) {
    __syncthreads();
    for (int idx = TID; idx < 16 * 34; idx += 256) {
      int r = idx / 34, c = idx % 34;
      int s = s0 - 1 + c;
      float v = 0.f;
      if (s >= 0 && s < 512) v = in[(((size_t)((b << 8) + ic0 + r)) << 9) + s];
      ins[r][c] = v;
    }
    for (int idx = TID; idx < 8192; idx += 256) {
      int rr = idx & 3;
      int o = (idx >> 2) & 63;
      int h = (idx >> 8) & 1;
      int i = idx >> 9;
      wsl[idx] = w[(((size_t)(ic0 + i)) << 11) + ((size_t)(o0 + o) << 3) + (h << 2) + rr];
    }
    __syncthreads();
#pragma unroll 2
    for (int i = 0; i < 16; i++) {
      float x0 = ins[i][2 * tx], x1 = ins[i][2 * tx + 1], x2 = ins[i][2 * tx + 2];
#pragma unroll
      for (int m = 0; m < 4; m++) {
        int om = (oy << 2) + m;
        float4 wa4 = *(const float4*)&wsl[(i << 9) + (om << 2)];
        float4 wb4 = *(const float4*)&wsl[(i << 9) + 256 + (om << 2)];
        float wa[4] = {wa4.x, wa4.y, wa4.z, wa4.w};
        float wb[4] = {wb4.x, wb4.y, wb4.z, wb4.w};
#pragma unroll
        for (int r = 0; r < 4; r++) {
          acc[0][m][r] += x1 * wa[r] + x0 * wb[r];
          acc[1][m][r] += x2 * wa[r] + x1 * wb[r];
        }
      }
    }
  }
#pragma unroll
  for (int j = 0; j < 2; j++) {
    int s1 = s0 + (tx << 1) + j;
#pragma unroll
    for (int m = 0; m < 4; m++) {
      int o = o0 + (oy << 2) + m;
      float bv = bias[o];
#pragma unroll
      for (int r = 0; r < 4; r++) {
        int t = (s1 << 2) + r - 2;
        if (t >= 0 && t < 2048) out[(((size_t)((b << 8) + o)) << 11) + t] = acc[j][m][r] + bv;
      }
    }
  }
}

__global__ __launch_bounds__(256) void conv_out_k(const float* __restrict__ in, const float* __restrict__ wP,
                                                  const float* __restrict__ bias, float* __restrict__ xhat) {
  int b = blockIdx.x >> 5;
  int t0 = (blockIdx.x & 31) << 6;
  int tx = TID & 63, oy = TID >> 6;
  __shared__ float ins[32][68];
  __shared__ float wsl[32 * 144];
  float acc[9];
#pragma unroll
  for (int m = 0; m < 9; m++) acc[m] = 0.f;
  for (int ic0 = 0; ic0 < 256; ic0 += 32) {
    __syncthreads();
    for (int idx = TID; idx < 32 * 66; idx += 256) {
      int r = idx / 66, c = idx % 66;
      int t = t0 - 1 + c;
      float v = 0.f;
      if (t >= 0 && t < 2048) v = in[(((size_t)((b << 8) + ic0 + r)) << 11) + t];
      ins[r][c] = v;
    }
    for (int idx = TID; idx < 32 * 144; idx += 256) {
      wsl[idx] = wP[ic0 * 144 + idx];
    }
    __syncthreads();
#pragma unroll 4
    for (int i = 0; i < 32; i++) {
      float x0 = ins[i][tx], x1 = ins[i][tx + 1], x2 = ins[i][tx + 2];
#pragma unroll
      for (int m = 0; m < 9; m++) {
        int o = oy * 9 + m;
        float4 wv = *(const float4*)&wsl[(i * 36 + o) << 2];
        acc[m] += wv.x * x0 + wv.y * x1 + wv.z * x2;
      }
    }
  }
  size_t orow = ((size_t)(b << 11) + t0 + tx) * 36;
#pragma unroll
  for (int m = 0; m < 9; m++) {
    int o = oy * 9 + m;
    xhat[orow + o] = acc[m] + bias[o];
  }
}

// ================= losses =================
__global__ __launch_bounds__(256) void loss_k(const float* __restrict__ x, const float* __restrict__ xh,
                                              const float* __restrict__ mask, float* __restrict__ scal) {
  float pos = 0.f, dir = 0.f, ms = 0.f;
  for (int n = blockIdx.x * blockDim.x + TID; n < 65536; n += gridDim.x * blockDim.x) {
    const float* xp = x + (size_t)n * 36;
    const float* hp = xh + (size_t)n * 36;
    float a[36], h[36];
#pragma unroll
    for (int d4 = 0; d4 < 36; d4 += 4) {
      *(float4*)&a[d4] = *(const float4*)&xp[d4];
      *(float4*)&h[d4] = *(const float4*)&hp[d4];
    }
#pragma unroll
    for (int d = 0; d < 36; d++) {
      if (d < 21 || (d >= 27 && d < 30)) {
        float df = h[d] - a[d];
        float ad = fabsf(df);
        pos += (ad < 1.f) ? 0.5f * df * df : ad - 0.5f;
      }
    }
    float mL = mask[2 * (size_t)n], mR = mask[2 * (size_t)n + 1];
    const int vb[4] = {21, 24, 30, 33};
    float mv[4] = {mL, mL, mR, mR};
#pragma unroll
    for (int v = 0; v < 4; v++) {
      int o = vb[v];
      float ax = a[o], ay = a[o + 1], az = a[o + 2];
      float hx = h[o], hy = h[o + 1], hz = h[o + 2];
      float an = sqrtf(ax * ax + ay * ay + az * az) + 1e-8f;
      float hn = sqrtf(hx * hx + hy * hy + hz * hz) + 1e-8f;
      float cs = (ax * hx + ay * hy + az * hz) / (an * hn);
      dir += (1.f - cs) * mv[v];
    }
    ms += 2.f * (mL + mR);
  }
  __shared__ float rp[256], rd[256], rm[256];
  rp[TID] = pos; rd[TID] = dir; rm[TID] = ms;
  __syncthreads();
  for (int st = 128; st > 0; st >>= 1) {
    if (TID < st) { rp[TID] += rp[TID + st]; rd[TID] += rd[TID + st]; rm[TID] += rm[TID + st]; }
    __syncthreads();
  }
  if (TID == 0) {
    atomicAdd(&scal[1], rp[0]);
    atomicAdd(&scal[2], rd[0]);
    atomicAdd(&scal[3], rm[0]);
  }
}

__global__ __launch_bounds__(256) void finalize_k(const float* __restrict__ counts, const float* __restrict__ scal,
                                                  float* __restrict__ tail) {
  __shared__ float red[256];
  float s = 0.f;
  for (int j = TID; j < 1024; j += 256) {
    float avg = counts[j] * (1.f / 16384.f);
    s += avg * logf(avg + 1e-10f);
  }
  red[TID] = s;
  __syncthreads();
  for (int st = 128; st > 0; st >>= 1) {
    if (TID < st) red[TID] += red[TID + st];
    __syncthreads();
  }
  if (TID == 0) {
    tail[0] = 1.25f * scal[0] * (1.f / 2097152.f);
    tail[1] = expf(-red[0]);
    tail[2] = scal[1] * (1.f / 65536.f);
    tail[3] = scal[2] / fmaxf(scal[3], 1.f);
  }
}

__global__ void codesf_k(const int* __restrict__ codes, float* __restrict__ o) {
  int n = blockIdx.x * blockDim.x + TID;
  if (n < 16384) o[n] = (float)codes[n];
}

// ================= host =================
extern "C" void kernel_launch(void* const* d_in, const int* in_sizes, int n_in,
                              void* d_out, int out_size, void* d_ws, size_t ws_size,
                              hipStream_t stream) {
  const float* x = (const float*)d_in[0];
  const float* mask = (const float*)d_in[1];
  const float* enc_in_w = (const float*)d_in[2];
  const float* enc_in_b = (const float*)d_in[3];
  const float* enc_gn1_g = (const float*)d_in[4];
  const float* enc_gn1_b = (const float*)d_in[5];
  const float* enc_c1_w = (const float*)d_in[6];
  const float* enc_c1_b = (const float*)d_in[7];
  const float* enc_gn2_g = (const float*)d_in[8];
  const float* enc_gn2_b = (const float*)d_in[9];
  const float* enc_c2_w = (const float*)d_in[10];
  const float* enc_c2_b = (const float*)d_in[11];
  const float* down_w = (const float*)d_in[12];
  const float* down_b = (const float*)d_in[13];
  const float* enc_out_w = (const float*)d_in[14];
  const float* enc_out_b = (const float*)d_in[15];
  const float* codebook = (const float*)d_in[16];
  const float* dec_in_w = (const float*)d_in[17];
  const float* dec_in_b = (const float*)d_in[18];
  const float* up_w = (const float*)d_in[19];
  const float* up_b = (const float*)d_in[20];
  const float* dec_gn1_g = (const float*)d_in[21];
  const float* dec_gn1_b = (const float*)d_in[22];
  const float* dec_c1_w = (const float*)d_in[23];
  const float* dec_c1_b = (const float*)d_in[24];
  const float* dec_gn2_g = (const float*)d_in[25];
  const float* dec_gn2_b = (const float*)d_in[26];
  const float* dec_c2_w = (const float*)d_in[27];
  const float* dec_c2_b = (const float*)d_in[28];
  const float* dec_out_w = (const float*)d_in[29];
  const float* dec_out_b = (const float*)d_in[30];

  char* W = (char*)d_ws;
  float* zE = (float*)(W + 0);                        // 8,388,608
  float* zQ = (float*)(W + 8388608);                  // 8,388,608
  int* codes = (int*)(W + 16777216);                  // 65,536
  float* counts = (float*)(W + 16842752);             // 4,096
  float* scal = (float*)(W + 16846848);               // 32
  float* csq = (float*)(W + 16846880);                // 4,096
  float* part_f = (float*)(W + 16850976);             // 4,096
  float* wf_enc_in = (float*)(W + 16855072);          // 110,592
  float* wf_enc_c1 = (float*)(W + 16965664);          // 3,145,728
  float* wf_enc_c2 = (float*)(W + 20111392);          // 3,145,728
  float* wf_down = (float*)(W + 23257120);            // 2,097,152
  float* wf_enc_out = (float*)(W + 25354272);         // 131,072
  float* wf_dec_in = (float*)(W + 25485344);          // 131,072
  float* wf_dec_c1 = (float*)(W + 25616416);          // 3,145,728
  float* wf_dec_c2 = (float*)(W + 28762144);          // 3,145,728
  float* wf_dec_out = (float*)(W + 31907872);         // 147,456
  // big region @48MiB: 3 x NB*256*2048 fp32 (33.5MB each) + dech
  float* f0 = (float*)(W + 50331648);
  float* f1 = (float*)(W + 50331648 + 33554432);
  float* f2 = (float*)(W + 50331648 + 2 * (size_t)33554432);
  float* dech = (float*)(W + 50331648 + 3 * (size_t)33554432);  // NB*256*512 f32 = 8.4MB

  dim3 blk(256);
  zero_k<<<dim3(5), blk, 0, stream>>>(counts, 1032);
  perm_oik_iko<<<dim3(128), blk, 0, stream>>>(enc_in_w, wf_enc_in, 1, 256, 36, 3);
  perm_oik_iko<<<dim3(1024), blk, 0, stream>>>(enc_c1_w, wf_enc_c1, 4, 256, 256, 3);
  perm_oik_iko<<<dim3(1024), blk, 0, stream>>>(enc_c2_w, wf_enc_c2, 4, 256, 256, 3);
  perm_oik_iko<<<dim3(1024), blk, 0, stream>>>(down_w, wf_down, 1, 256, 256, 8);
  perm_oik_iko<<<dim3(128), blk, 0, stream>>>(enc_out_w, wf_enc_out, 1, 128, 256, 1);
  perm_oik_iko<<<dim3(128), blk, 0, stream>>>(dec_in_w, wf_dec_in, 1, 256, 128, 1);
  perm_oik_iko<<<dim3(1024), blk, 0, stream>>>(dec_c1_w, wf_dec_c1, 4, 256, 256, 3);
  perm_oik_iko<<<dim3(1024), blk, 0, stream>>>(dec_c2_w, wf_dec_c2, 4, 256, 256, 3);
  perm_decout<<<dim3(64), blk, 0, stream>>>(dec_out_w, wf_dec_out);
  csq_f32<<<dim3(4), blk, 0, stream>>>(codebook, csq);

  const int GN = NB * 8 * 4;  // 512 blocks

  // ---- encoder (fp32), 2 chunks of NB=16 ----
  for (int ci = 0; ci < 2; ci++) {
    int b0 = ci * NB;
    conv_in_k<<<dim3(NB * 32, 4), blk, 0, stream>>>(x + (size_t)b0 * 2048 * 36, wf_enc_in, enc_in_b, f0);
    for (int i = 0; i < 4; i++) {
      gn_part_f32<<<dim3(GN), blk, 0, stream>>>(f0, part_f);
      gn_apply_f32<<<dim3(GN), blk, 0, stream>>>(f0, f1, part_f, enc_gn1_g + i * 256, enc_gn1_b + i * 256);
      conv3_k<<<dim3(NB * 32, 4), blk, 0, stream>>>(f1, wf_enc_c1 + i * 196608, enc_c1_b + i * 256, nullptr, f2);
      gn_part_f32<<<dim3(GN), blk, 0, stream>>>(f2, part_f);
      gn_apply_f32<<<dim3(GN), blk, 0, stream>>>(f2, f2, part_f, enc_gn2_g + i * 256, enc_gn2_b + i * 256);
      conv3_k<<<dim3(NB * 32, 4), blk, 0, stream>>>(f2, wf_enc_c2 + i * 196608, enc_c2_b + i * 256, f0, f0);
    }
    conv_down_k<<<dim3(NB * 8, 4), blk, 0, stream>>>(f0, wf_down, down_b, f1);
    conv1x1_k<<<dim3(NB * 8, 2), blk, 0, stream>>>(f1, wf_enc_out, enc_out_b, zE + (size_t)b0 * 128 * 512, 256, 128);
  }

  // ---- quantize ----
  vq_tiled<<<dim3(256), blk, 0, stream>>>(zE, codebook, csq, codes);
  count_k<<<dim3(64), blk, 0, stream>>>(codes, counts);
  gather_k<<<dim3(512), blk, 0, stream>>>(codebook, codes, zE, zQ, &scal[0]);

  // ---- decoder (fp32), 2 chunks of NB=16 ----
  float* xhat = (float*)d_out;
  for (int ci = 0; ci < 2; ci++) {
    int b0 = ci * NB;
    conv1x1_k<<<dim3(NB * 8, 4), blk, 0, stream>>>(zQ + (size_t)b0 * 128 * 512, wf_dec_in, dec_in_b, dech, 128, 256);
    conv_up_k<<<dim3(NB * 17, 4), blk, 0, stream>>>(dech, up_w, up_b, f0);
    for (int i = 0; i < 4; i++) {
      gn_part_f32<<<dim3(GN), blk, 0, stream>>>(f0, part_f);
      gn_apply_f32<<<dim3(GN), blk, 0, stream>>>(f0, f1, part_f, dec_gn1_g + i * 256, dec_gn1_b + i * 256);
      conv3_k<<<dim3(NB * 32, 4), blk, 0, stream>>>(f1, wf_dec_c1 + i * 196608, dec_c1_b + i * 256, nullptr, f2);
      gn_part_f32<<<dim3(GN), blk, 0, stream>>>(f2, part_f);
      gn_apply_f32<<<dim3(GN), blk, 0, stream>>>(f2, f2, part_f, dec_gn2_g + i * 256, dec_gn2_b + i * 256);
      conv3_k<<<dim3(NB * 32, 4), blk, 0, stream>>>(f2, wf_dec_c2 + i * 196608, dec_c2_b + i * 256, f0, f0);
    }
    conv_out_k<<<dim3(NB * 32), blk, 0, stream>>>(f0, wf_dec_out, dec_out_b, xhat + (size_t)b0 * 2048 * 36);
  }

  // ---- losses / scalars ----
  loss_k<<<dim3(256), blk, 0, stream>>>(x, xhat, mask, scal);
  finalize_k<<<dim3(1), blk, 0, stream>>>(counts, scal, (float*)d_out + 2375680);
  codesf_k<<<dim3(64), blk, 0, stream>>>(codes, (float*)d_out + 2359296);
}

// Round 8
// 10197.424 us; speedup vs baseline: 1.9736x; 1.0124x over previous
//
#include <hip/hip_runtime.h>
#include <cstddef>
#include <cstdint>

// VQ-VAE 1D forward — full fp32 pipeline.
// Codes: reference argmin follows fp32 dist = fl(zsq+csq) - fl(2*zc), first-index ties.
// vq_tiled is BYTE-IDENTICAL to the r7-passing kernel. Encoder conv chains keep the same
// per-output FMA expression/order as r7 (retile + GN-fusion are chain-preserving).
// R8: conv3 retiled to t=128 (two bank-safe 64-halves, ic-chunk 16) with GN+SiLU fused
// into staging (gn_apply kernels removed).
// d_out: x_hat (B,T,36) | codes as float (B,512) | [loss_vq, perplexity, loss_pos, loss_dir]

#define TID ((int)threadIdx.x)
#define NB 16  // batches per chunk (both phases)

__device__ __forceinline__ float silu_f(float y) { return y / (1.f + expf(-y)); }

// ================= weight prep =================
__global__ void perm_oik_iko(const float* __restrict__ src, float* __restrict__ dst,
                             int R, int O, int I, int K) {
  int n = R * O * I * K;
  for (int idx = blockIdx.x * blockDim.x + TID; idx < n; idx += gridDim.x * blockDim.x) {
    int o = idx % O;
    int k = (idx / O) % K;
    int i = (idx / (O * K)) % I;
    int r = idx / (O * K * I);
    dst[idx] = src[((r * O + o) * I + i) * K + k];
  }
}

__global__ void perm_decout(const float* __restrict__ src, float* __restrict__ dst) {
  int n = 256 * 36 * 4;
  for (int idx = blockIdx.x * blockDim.x + TID; idx < n; idx += gridDim.x * blockDim.x) {
    int k = idx & 3;
    int o = (idx >> 2) % 36;
    int i = idx / 144;
    dst[idx] = (k < 3) ? src[(o * 256 + i) * 3 + k] : 0.f;
  }
}

__global__ void zero_k(float* p, int n) {
  int i = blockIdx.x * blockDim.x + TID;
  if (i < n) p[i] = 0.f;
}

// csq[j] = fp32 sequential sum of fl(c*c)
__global__ void csq_f32(const float* __restrict__ cb, float* __restrict__ csq) {
  int j = blockIdx.x * blockDim.x + TID;
  if (j < 1024) {
    float s = 0.f;
    for (int c = 0; c < 128; c++) { float v = cb[j * 128 + c]; s += v * v; }
    csq[j] = s;
  }
}

// ================= GroupNorm stats (apply is fused into conv3) =================
__global__ __launch_bounds__(256) void gn_part_f32(const float* __restrict__ in, float* __restrict__ part) {
  int bg = blockIdx.x >> 2, q = blockIdx.x & 3;
  const float4* src = (const float4*)(in + ((size_t)bg << 16) + ((size_t)q << 14));
  float s1 = 0.f, s2 = 0.f;
  for (int f = TID; f < 4096; f += 256) {
    float4 v = src[f];
    s1 += v.x + v.y + v.z + v.w;
    s2 += v.x * v.x + v.y * v.y + v.z * v.z + v.w * v.w;
  }
  __shared__ float r1[256], r2[256];
  r1[TID] = s1; r2[TID] = s2;
  __syncthreads();
  for (int st = 128; st > 0; st >>= 1) {
    if (TID < st) { r1[TID] += r1[TID + st]; r2[TID] += r2[TID + st]; }
    __syncthreads();
  }
  if (TID == 0) { part[blockIdx.x * 2] = r1[0]; part[blockIdx.x * 2 + 1] = r2[0]; }
}

// ================= fp32 convs =================
// input conv 36->256, k=3. grid=(NB*32,4)
__global__ __launch_bounds__(256) void conv_in_k(const float* __restrict__ x, const float* __restrict__ wT,
                                                 const float* __restrict__ bias, float* __restrict__ out) {
  int b = blockIdx.x >> 5;
  int t0 = (blockIdx.x & 31) << 6;
  int o0 = blockIdx.y << 6;
  int tx = TID & 15, oy = TID >> 4;
  __shared__ float ins[36][68];
  __shared__ float wsl[36 * 192];
  for (int idx = TID; idx < 36 * 66; idx += 256) {
    int i = idx % 36, c = idx / 36;
    int t = t0 - 1 + c;
    float v = 0.f;
    if (t >= 0 && t < 2048) v = x[((size_t)(b * 2048 + t)) * 36 + i];
    ins[i][c] = v;
  }
  for (int idx = TID; idx < 36 * 192; idx += 256) {
    int o = idx & 63;
    int kk = (idx >> 6) % 3;
    int i = idx / 192;
    wsl[idx] = wT[(i * 3 + kk) * 256 + o0 + o];
  }
  __syncthreads();
  float acc[4][4];
#pragma unroll
  for (int m = 0; m < 4; m++)
#pragma unroll
    for (int n = 0; n < 4; n++) acc[m][n] = 0.f;
  for (int i = 0; i < 36; i++) {
    float xv[6];
    float4 x4 = *(const float4*)&ins[i][tx << 2];
    xv[0] = x4.x; xv[1] = x4.y; xv[2] = x4.z; xv[3] = x4.w;
    xv[4] = ins[i][(tx << 2) + 4];
    xv[5] = ins[i][(tx << 2) + 5];
    const float* wrow = &wsl[i * 192];
    float wv[3][4];
    *(float4*)wv[0] = *(const float4*)&wrow[oy << 2];
    *(float4*)wv[1] = *(const float4*)&wrow[64 + (oy << 2)];
    *(float4*)wv[2] = *(const float4*)&wrow[128 + (oy << 2)];
#pragma unroll
    for (int m = 0; m < 4; m++)
#pragma unroll
      for (int n = 0; n < 4; n++)
        acc[m][n] += wv[0][m] * xv[n] + wv[1][m] * xv[n + 1] + wv[2][m] * xv[n + 2];
  }
  int obase = o0 + (oy << 2);
#pragma unroll
  for (int m = 0; m < 4; m++) {
    int o = obase + m;
    float bv = bias[o];
    size_t rowo = (((size_t)((b << 8) + o)) << 11) + t0 + (tx << 2);
#pragma unroll
    for (int n = 0; n < 4; n++) out[rowo + n] = acc[m][n] + bv;
  }
}

// k=3 conv 256->256 with FUSED GroupNorm+SiLU on the input (stats from part[]).
// t-tile 128 as two bank-safe 64-halves; o-tile 64; ic-chunk 16. grid=(NB*16,4).
// Per-output FMA chain identical to r7's conv3_k (same expression, same ic order).
__global__ __launch_bounds__(256) void conv3_gn_k(const float* __restrict__ in, const float* __restrict__ part,
                                                  const float* __restrict__ gamma, const float* __restrict__ beta,
                                                  const float* __restrict__ wT, const float* __restrict__ bias,
                                                  const float* __restrict__ src, float* __restrict__ out) {
  int b = blockIdx.x >> 4;
  int t0 = (blockIdx.x & 15) << 7;
  int o0 = blockIdx.y << 6;
  int tx = TID & 15, oy = TID >> 4;
  __shared__ float ins[16][132];
  __shared__ float wsl[16 * 192];
  float acc[4][8];
#pragma unroll
  for (int m = 0; m < 4; m++)
#pragma unroll
    for (int n = 0; n < 8; n++) acc[m][n] = 0.f;
  for (int ic0 = 0; ic0 < 256; ic0 += 16) {
    // GN stats for this chunk's channel group (all 16 ch in one 32-ch group)
    int g = ic0 >> 5;
    const float* pp = part + ((size_t)((b << 3) + g)) * 8;
    float s1 = pp[0] + pp[2] + pp[4] + pp[6];
    float s2 = pp[1] + pp[3] + pp[5] + pp[7];
    float mu = s1 * (1.f / 65536.f);
    float var = s2 * (1.f / 65536.f) - mu * mu;
    float rs = rsqrtf(var + 1e-5f);
    __syncthreads();
    for (int idx = TID; idx < 16 * 132; idx += 256) {
      int r = idx / 132, c = idx - r * 132;
      int t = t0 - 1 + c;
      float v = 0.f;
      if (c < 130 && t >= 0 && t < 2048) {
        int ch = ic0 + r;
        float h = in[(((size_t)((b << 8) + ch)) << 11) + t];
        float a = rs * gamma[ch];
        float bb = beta[ch] - mu * a;
        float y = h * a + bb;
        v = y / (1.f + expf(-y));
      }
      ins[r][c] = v;
    }
    for (int idx4 = TID; idx4 < 768; idx4 += 256) {
      int i = idx4 / 48;
      int rem = idx4 - i * 48;
      int kk = rem >> 4;
      int o4 = (rem & 15) << 2;
      *(float4*)&wsl[i * 192 + kk * 64 + o4] =
          *(const float4*)&wT[((ic0 + i) * 3 + kk) * 256 + o0 + o4];
    }
    __syncthreads();
#pragma unroll 2
    for (int i = 0; i < 16; i++) {
      float xv[6], xw[6];
      float4 x4 = *(const float4*)&ins[i][tx << 2];
      xv[0] = x4.x; xv[1] = x4.y; xv[2] = x4.z; xv[3] = x4.w;
      xv[4] = ins[i][(tx << 2) + 4];
      xv[5] = ins[i][(tx << 2) + 5];
      float4 x42 = *(const float4*)&ins[i][64 + (tx << 2)];
      xw[0] = x42.x; xw[1] = x42.y; xw[2] = x42.z; xw[3] = x42.w;
      xw[4] = ins[i][64 + (tx << 2) + 4];
      xw[5] = ins[i][64 + (tx << 2) + 5];
      const float* wrow = &wsl[i * 192];
      float wv[3][4];
      *(float4*)wv[0] = *(const float4*)&wrow[oy << 2];
      *(float4*)wv[1] = *(const float4*)&wrow[64 + (oy << 2)];
      *(float4*)wv[2] = *(const float4*)&wrow[128 + (oy << 2)];
#pragma unroll
      for (int m = 0; m < 4; m++)
#pragma unroll
        for (int n = 0; n < 4; n++) {
          acc[m][n] += wv[0][m] * xv[n] + wv[1][m] * xv[n + 1] + wv[2][m] * xv[n + 2];
          acc[m][n + 4] += wv[0][m] * xw[n] + wv[1][m] * xw[n + 1] + wv[2][m] * xw[n + 2];
        }
    }
  }
  int obase = o0 + (oy << 2);
#pragma unroll
  for (int m = 0; m < 4; m++) {
    int o = obase + m;
    float bv = bias[o];
    size_t rowo = (((size_t)((b << 8) + o)) << 11) + t0 + (tx << 2);
#pragma unroll
    for (int n = 0; n < 4; n++) {
      float v = acc[m][n] + bv;
      if (src) v += src[rowo + n];
      out[rowo + n] = v;
    }
    size_t rowo2 = rowo + 64;
#pragma unroll
    for (int n = 0; n < 4; n++) {
      float v = acc[m][n + 4] + bv;
      if (src) v += src[rowo2 + n];
      out[rowo2 + n] = v;
    }
  }
}

// down conv k=8 stride 4, Tout=512. grid=(NB*8,4)
__global__ __launch_bounds__(256) void conv_down_k(const float* __restrict__ in, const float* __restrict__ wT,
                                                   const float* __restrict__ bias, float* __restrict__ out) {
  int b = blockIdx.x >> 3;
  int to0 = (blockIdx.x & 7) << 6;
  int o0 = blockIdx.y << 6;
  int tx = TID & 15, oy = TID >> 4;
  __shared__ float ins[16][264];
  __shared__ float wsl[16 * 512];
  float acc[4][4];
#pragma unroll
  for (int m = 0; m < 4; m++)
#pragma unroll
    for (int n = 0; n < 4; n++) acc[m][n] = 0.f;
  for (int ic0 = 0; ic0 < 256; ic0 += 16) {
    __syncthreads();
    for (int idx = TID; idx < 16 * 260; idx += 256) {
      int r = idx / 260, c = idx % 260;
      int s = (to0 << 2) - 2 + c;
      float v = 0.f;
      if (s >= 0 && s < 2048) v = in[(((size_t)((b << 8) + ic0 + r)) << 11) + s];
      ins[r][c] = v;
    }
    for (int idx = TID; idx < 16 * 512; idx += 256) {
      int o = idx & 63;
      int kk = (idx >> 6) & 7;
      int i = idx >> 9;
      wsl[idx] = wT[((ic0 + i) * 8 + kk) * 256 + o0 + o];
    }
    __syncthreads();
#pragma unroll 2
    for (int i = 0; i < 16; i++) {
      float xv[20];
#pragma unroll
      for (int q = 0; q < 5; q++) *(float4*)&xv[q * 4] = *(const float4*)&ins[i][(tx << 4) + (q << 2)];
      float wv[8][4];
#pragma unroll
      for (int kk = 0; kk < 8; kk++) *(float4*)wv[kk] = *(const float4*)&wsl[(i << 9) + (kk << 6) + (oy << 2)];
#pragma unroll
      for (int n = 0; n < 4; n++)
#pragma unroll
        for (int kk = 0; kk < 8; kk++) {
          float xval = xv[(n << 2) + kk];
#pragma unroll
          for (int m = 0; m < 4; m++) acc[m][n] += wv[kk][m] * xval;
        }
    }
  }
  int obase = o0 + (oy << 2);
#pragma unroll
  for (int m = 0; m < 4; m++) {
    int o = obase + m;
    float bv = bias[o];
    size_t rowo = (((size_t)((b << 8) + o)) << 9) + to0 + (tx << 2);
#pragma unroll
    for (int n = 0; n < 4; n++) out[rowo + n] = acc[m][n] + bv;
  }
}

// 1x1 conv, T=512. grid=(NB*8, O/64)
__global__ __launch_bounds__(256) void conv1x1_k(const float* __restrict__ in, const float* __restrict__ wIO,
                                                 const float* __restrict__ bias, float* __restrict__ out,
                                                 int Kc, int O) {
  int b = blockIdx.x >> 3;
  int t0 = (blockIdx.x & 7) << 6;
  int o0 = blockIdx.y << 6;
  int tx = TID & 15, oy = TID >> 4;
  __shared__ float xs[32][64];
  __shared__ float wsd[32][64];
  float acc[4][4];
#pragma unroll
  for (int m = 0; m < 4; m++)
#pragma unroll
    for (int n = 0; n < 4; n++) acc[m][n] = 0.f;
  for (int ic0 = 0; ic0 < Kc; ic0 += 32) {
    __syncthreads();
    for (int idx = TID; idx < 2048; idx += 256) {
      int r = idx >> 6, c = idx & 63;
      xs[r][c] = in[((size_t)(b * Kc + ic0 + r) << 9) + t0 + c];
      wsd[r][c] = wIO[(ic0 + r) * O + o0 + c];
    }
    __syncthreads();
#pragma unroll 8
    for (int i = 0; i < 32; i++) {
      float4 xvv = *(const float4*)&xs[i][tx << 2];
      float4 wvv = *(const float4*)&wsd[i][oy << 2];
      float xv[4] = {xvv.x, xvv.y, xvv.z, xvv.w};
      float wv[4] = {wvv.x, wvv.y, wvv.z, wvv.w};
#pragma unroll
      for (int m = 0; m < 4; m++)
#pragma unroll
        for (int n = 0; n < 4; n++) acc[m][n] += wv[m] * xv[n];
    }
  }
#pragma unroll
  for (int m = 0; m < 4; m++) {
    int o = o0 + (oy << 2) + m;
    float bv = bias[o];
    size_t rowo = ((size_t)(b * O + o) << 9) + t0 + (tx << 2);
#pragma unroll
    for (int n = 0; n < 4; n++) out[rowo + n] = acc[m][n] + bv;
  }
}

// ===== VQ tiled: BYTE-IDENTICAL to r7-passing kernel — do not touch =====
__global__ __launch_bounds__(256) void vq_tiled(const float* __restrict__ zE,
                                                const float* __restrict__ cb,
                                                const float* __restrict__ csq,
                                                int* __restrict__ codes) {
  int b = blockIdx.x >> 3;
  int t0 = (blockIdx.x & 7) << 6;
  int cq = TID & 15, pq = TID >> 4;
  __shared__ float Zs[128][66];
  __shared__ float Cs[64][129];
  __shared__ float zsqs[64];
  __shared__ float bd[64][17];
  __shared__ int bix[64][17];
  for (int idx = TID; idx < 128 * 64; idx += 256) {
    int c = idx >> 6, p = idx & 63;
    Zs[c][p] = zE[((size_t)(b * 128 + c) << 9) + t0 + p];
  }
  __syncthreads();
  if (TID < 64) {
    float s = 0.f;
    for (int c = 0; c < 128; c++) { float v = Zs[c][TID]; s += v * v; }
    zsqs[TID] = s;
  }
  float best[4];
  int bidx[4];
#pragma unroll
  for (int n = 0; n < 4; n++) { best[n] = 3.4e38f; bidx[n] = 0; }
  const int j0 = cq << 2;
  for (int cg = 0; cg < 16; cg++) {
    __syncthreads();
    for (int idx = TID; idx < 64 * 128; idx += 256) {
      int j = idx >> 7, c = idx & 127;
      Cs[j][c] = cb[((cg << 6) + j) * 128 + c];
    }
    __syncthreads();
    float acc[4][4];
#pragma unroll
    for (int u = 0; u < 4; u++)
#pragma unroll
      for (int n = 0; n < 4; n++) acc[u][n] = 0.f;
    for (int c = 0; c < 128; c++) {
      float4 zv4 = *(const float4*)&Zs[c][pq << 2];
      float zv[4] = {zv4.x, zv4.y, zv4.z, zv4.w};
      float cv[4];
#pragma unroll
      for (int u = 0; u < 4; u++) cv[u] = Cs[j0 + u][c];
#pragma unroll
      for (int u = 0; u < 4; u++)
#pragma unroll
        for (int n = 0; n < 4; n++) acc[u][n] += zv[n] * cv[u];
    }
#pragma unroll
    for (int u = 0; u < 4; u++) {
      int code = (cg << 6) + j0 + u;
      float cs_ = csq[code];
#pragma unroll
      for (int n = 0; n < 4; n++) {
        float A = zsqs[(pq << 2) + n] + cs_;
        float B = 2.0f * acc[u][n];
        float d = A - B;
        if (d < best[n]) { best[n] = d; bidx[n] = code; }
      }
    }
  }
  __syncthreads();
#pragma unroll
  for (int n = 0; n < 4; n++) { bd[(pq << 2) + n][cq] = best[n]; bix[(pq << 2) + n][cq] = bidx[n]; }
  __syncthreads();
  if (TID < 64) {
    float bb = bd[TID][0];
    int bj = bix[TID][0];
    for (int q = 1; q < 16; q++) {
      float d = bd[TID][q];
      int j = bix[TID][q];
      if (d < bb || (d == bb && j < bj)) { bb = d; bj = j; }
    }
    codes[(b << 9) + t0 + TID] = bj;
  }
}

// ================= VQ bookkeeping =================
__global__ void count_k(const int* __restrict__ codes, float* __restrict__ counts) {
  int n = blockIdx.x * blockDim.x + TID;
  if (n < 16384) atomicAdd(&counts[codes[n]], 1.f);
}

__global__ __launch_bounds__(256) void gather_k(const float* __restrict__ cb, const int* __restrict__ codes,
                                                const float* __restrict__ zE, float* __restrict__ zQ,
                                                float* __restrict__ vqsum) {
  double part = 0.;
  const int total = 32 * 128 * 512;
  for (int idx = blockIdx.x * blockDim.x + TID; idx < total; idx += gridDim.x * blockDim.x) {
    int t = idx & 511;
    int c = (idx >> 9) & 127;
    int b = idx >> 16;
    int code = codes[(b << 9) + t];
    float q = cb[code * 128 + c];
    double d = (double)q - (double)zE[idx];
    zQ[idx] = q;
    part += d * d;
  }
  __shared__ double red[256];
  red[TID] = part;
  __syncthreads();
  for (int st = 128; st > 0; st >>= 1) {
    if (TID < st) red[TID] += red[TID + st];
    __syncthreads();
  }
  if (TID == 0) atomicAdd(vqsum, (float)red[0]);
}

// ================= decoder-only convs =================
__global__ __launch_bounds__(256) void conv_up_k(const float* __restrict__ in, const float* __restrict__ w,
                                                 const float* __restrict__ bias, float* __restrict__ out) {
  int b = blockIdx.x / 17;
  int s0 = (blockIdx.x % 17) << 5;
  int o0 = blockIdx.y << 6;
  int tx = TID & 15, oy = TID >> 4;
  __shared__ float ins[16][36];
  __shared__ float wsl[16 * 512];
  float acc[2][4][4];
#pragma unroll
  for (int j = 0; j < 2; j++)
#pragma unroll
    for (int m = 0; m < 4; m++)
#pragma unroll
      for (int r = 0; r < 4; r++) acc[j][m][r] = 0.f;
  for (int ic0 = 0; ic0 < 256; ic0 += 16) {
    __syncthreads();
    for (int idx = TID; idx < 16 * 34; idx += 256) {
      int r = idx / 34, c = idx % 34;
      int s = s0 - 1 + c;
      float v = 0.f;
      if (s >= 0 && s < 512) v = in[(((size_t)((b << 8) + ic0 + r)) << 9) + s];
      ins[r][c] = v;
    }
    for (int idx = TID; idx < 8192; idx += 256) {
      int rr = idx & 3;
      int o = (idx >> 2) & 63;
      int h = (idx >> 8) & 1;
      int i = idx >> 9;
      wsl[idx] = w[(((size_t)(ic0 + i)) << 11) + ((size_t)(o0 + o) << 3) + (h << 2) + rr];
    }
    __syncthreads();
#pragma unroll 2
    for (int i = 0; i < 16; i++) {
      float x0 = ins[i][2 * tx], x1 = ins[i][2 * tx + 1], x2 = ins[i][2 * tx + 2];
#pragma unroll
      for (int m = 0; m < 4; m++) {
        int om = (oy << 2) + m;
        float4 wa4 = *(const float4*)&wsl[(i << 9) + (om << 2)];
        float4 wb4 = *(const float4*)&wsl[(i << 9) + 256 + (om << 2)];
        float wa[4] = {wa4.x, wa4.y, wa4.z, wa4.w};
        float wb[4] = {wb4.x, wb4.y, wb4.z, wb4.w};
#pragma unroll
        for (int r = 0; r < 4; r++) {
          acc[0][m][r] += x1 * wa[r] + x0 * wb[r];
          acc[1][m][r] += x2 * wa[r] + x1 * wb[r];
        }
      }
    }
  }
#pragma unroll
  for (int j = 0; j < 2; j++) {
    int s1 = s0 + (tx << 1) + j;
#pragma unroll
    for (int m = 0; m < 4; m++) {
      int o = o0 + (oy << 2) + m;
      float bv = bias[o];
#pragma unroll
      for (int r = 0; r < 4; r++) {
        int t = (s1 << 2) + r - 2;
        if (t >= 0 && t < 2048) out[(((size_t)((b << 8) + o)) << 11) + t] = acc[j][m][r] + bv;
      }
    }
  }
}

__global__ __launch_bounds__(256) void conv_out_k(const float* __restrict__ in, const float* __restrict__ wP,
                                                  const float* __restrict__ bias, float* __restrict__ xhat) {
  int b = blockIdx.x >> 5;
  int t0 = (blockIdx.x & 31) << 6;
  int tx = TID & 63, oy = TID >> 6;
  __shared__ float ins[32][68];
  __shared__ float wsl[32 * 144];
  float acc[9];
#pragma unroll
  for (int m = 0; m < 9; m++) acc[m] = 0.f;
  for (int ic0 = 0; ic0 < 256; ic0 += 32) {
    __syncthreads();
    for (int idx = TID; idx < 32 * 66; idx += 256) {
      int r = idx / 66, c = idx % 66;
      int t = t0 - 1 + c;
      float v = 0.f;
      if (t >= 0 && t < 2048) v = in[(((size_t)((b << 8) + ic0 + r)) << 11) + t];
      ins[r][c] = v;
    }
    for (int idx = TID; idx < 32 * 144; idx += 256) {
      wsl[idx] = wP[ic0 * 144 + idx];
    }
    __syncthreads();
#pragma unroll 4
    for (int i = 0; i < 32; i++) {
      float x0 = ins[i][tx], x1 = ins[i][tx + 1], x2 = ins[i][tx + 2];
#pragma unroll
      for (int m = 0; m < 9; m++) {
        int o = oy * 9 + m;
        float4 wv = *(const float4*)&wsl[(i * 36 + o) << 2];
        acc[m] += wv.x * x0 + wv.y * x1 + wv.z * x2;
      }
    }
  }
  size_t orow = ((size_t)(b << 11) + t0 + tx) * 36;
#pragma unroll
  for (int m = 0; m < 9; m++) {
    int o = oy * 9 + m;
    xhat[orow + o] = acc[m] + bias[o];
  }
}

// ================= losses =================
__global__ __launch_bounds__(256) void loss_k(const float* __restrict__ x, const float* __restrict__ xh,
                                              const float* __restrict__ mask, float* __restrict__ scal) {
  float pos = 0.f, dir = 0.f, ms = 0.f;
  for (int n = blockIdx.x * blockDim.x + TID; n < 65536; n += gridDim.x * blockDim.x) {
    const float* xp = x + (size_t)n * 36;
    const float* hp = xh + (size_t)n * 36;
    float a[36], h[36];
#pragma unroll
    for (int d4 = 0; d4 < 36; d4 += 4) {
      *(float4*)&a[d4] = *(const float4*)&xp[d4];
      *(float4*)&h[d4] = *(const float4*)&hp[d4];
    }
#pragma unroll
    for (int d = 0; d < 36; d++) {
      if (d < 21 || (d >= 27 && d < 30)) {
        float df = h[d] - a[d];
        float ad = fabsf(df);
        pos += (ad < 1.f) ? 0.5f * df * df : ad - 0.5f;
      }
    }
    float mL = mask[2 * (size_t)n], mR = mask[2 * (size_t)n + 1];
    const int vb[4] = {21, 24, 30, 33};
    float mv[4] = {mL, mL, mR, mR};
#pragma unroll
    for (int v = 0; v < 4; v++) {
      int o = vb[v];
      float ax = a[o], ay = a[o + 1], az = a[o + 2];
      float hx = h[o], hy = h[o + 1], hz = h[o + 2];
      float an = sqrtf(ax * ax + ay * ay + az * az) + 1e-8f;
      float hn = sqrtf(hx * hx + hy * hy + hz * hz) + 1e-8f;
      float cs = (ax * hx + ay * hy + az * hz) / (an * hn);
      dir += (1.f - cs) * mv[v];
    }
    ms += 2.f * (mL + mR);
  }
  __shared__ float rp[256], rd[256], rm[256];
  rp[TID] = pos; rd[TID] = dir; rm[TID] = ms;
  __syncthreads();
  for (int st = 128; st > 0; st >>= 1) {
    if (TID < st) { rp[TID] += rp[TID + st]; rd[TID] += rd[TID + st]; rm[TID] += rm[TID + st]; }
    __syncthreads();
  }
  if (TID == 0) {
    atomicAdd(&scal[1], rp[0]);
    atomicAdd(&scal[2], rd[0]);
    atomicAdd(&scal[3], rm[0]);
  }
}

__global__ __launch_bounds__(256) void finalize_k(const float* __restrict__ counts, const float* __restrict__ scal,
                                                  float* __restrict__ tail) {
  __shared__ float red[256];
  float s = 0.f;
  for (int j = TID; j < 1024; j += 256) {
    float avg = counts[j] * (1.f / 16384.f);
    s += avg * logf(avg + 1e-10f);
  }
  red[TID] = s;
  __syncthreads();
  for (int st = 128; st > 0; st >>= 1) {
    if (TID < st) red[TID] += red[TID + st];
    __syncthreads();
  }
  if (TID == 0) {
    tail[0] = 1.25f * scal[0] * (1.f / 2097152.f);
    tail[1] = expf(-red[0]);
    tail[2] = scal[1] * (1.f / 65536.f);
    tail[3] = scal[2] / fmaxf(scal[3], 1.f);
  }
}

__global__ void codesf_k(const int* __restrict__ codes, float* __restrict__ o) {
  int n = blockIdx.x * blockDim.x + TID;
  if (n < 16384) o[n] = (float)codes[n];
}

// ================= host =================
extern "C" void kernel_launch(void* const* d_in, const int* in_sizes, int n_in,
                              void* d_out, int out_size, void* d_ws, size_t ws_size,
                              hipStream_t stream) {
  const float* x = (const float*)d_in[0];
  const float* mask = (const float*)d_in[1];
  const float* enc_in_w = (const float*)d_in[2];
  const float* enc_in_b = (const float*)d_in[3];
  const float* enc_gn1_g = (const float*)d_in[4];
  const float* enc_gn1_b = (const float*)d_in[5];
  const float* enc_c1_w = (const float*)d_in[6];
  const float* enc_c1_b = (const float*)d_in[7];
  const float* enc_gn2_g = (const float*)d_in[8];
  const float* enc_gn2_b = (const float*)d_in[9];
  const float* enc_c2_w = (const float*)d_in[10];
  const float* enc_c2_b = (const float*)d_in[11];
  const float* down_w = (const float*)d_in[12];
  const float* down_b = (const float*)d_in[13];
  const float* enc_out_w = (const float*)d_in[14];
  const float* enc_out_b = (const float*)d_in[15];
  const float* codebook = (const float*)d_in[16];
  const float* dec_in_w = (const float*)d_in[17];
  const float* dec_in_b = (const float*)d_in[18];
  const float* up_w = (const float*)d_in[19];
  const float* up_b = (const float*)d_in[20];
  const float* dec_gn1_g = (const float*)d_in[21];
  const float* dec_gn1_b = (const float*)d_in[22];
  const float* dec_c1_w = (const float*)d_in[23];
  const float* dec_c1_b = (const float*)d_in[24];
  const float* dec_gn2_g = (const float*)d_in[25];
  const float* dec_gn2_b = (const float*)d_in[26];
  const float* dec_c2_w = (const float*)d_in[27];
  const float* dec_c2_b = (const float*)d_in[28];
  const float* dec_out_w = (const float*)d_in[29];
  const float* dec_out_b = (const float*)d_in[30];

  char* W = (char*)d_ws;
  float* zE = (float*)(W + 0);                        // 8,388,608
  float* zQ = (float*)(W + 8388608);                  // 8,388,608
  int* codes = (int*)(W + 16777216);                  // 65,536
  float* counts = (float*)(W + 16842752);             // 4,096
  float* scal = (float*)(W + 16846848);               // 32
  float* csq = (float*)(W + 16846880);                // 4,096
  float* part_f = (float*)(W + 16850976);             // 4,096
  float* wf_enc_in = (float*)(W + 16855072);          // 110,592
  float* wf_enc_c1 = (float*)(W + 16965664);          // 3,145,728
  float* wf_enc_c2 = (float*)(W + 20111392);          // 3,145,728
  float* wf_down = (float*)(W + 23257120);            // 2,097,152
  float* wf_enc_out = (float*)(W + 25354272);         // 131,072
  float* wf_dec_in = (float*)(W + 25485344);          // 131,072
  float* wf_dec_c1 = (float*)(W + 25616416);          // 3,145,728
  float* wf_dec_c2 = (float*)(W + 28762144);          // 3,145,728
  float* wf_dec_out = (float*)(W + 31907872);         // 147,456
  // big region @48MiB: f0, f2 (33.5MB each) + dech
  float* f0 = (float*)(W + 50331648);
  float* f2 = (float*)(W + 50331648 + 33554432);
  float* dech = (float*)(W + 50331648 + 2 * (size_t)33554432);  // NB*256*512 f32 = 8.4MB

  dim3 blk(256);
  zero_k<<<dim3(5), blk, 0, stream>>>(counts, 1032);
  perm_oik_iko<<<dim3(128), blk, 0, stream>>>(enc_in_w, wf_enc_in, 1, 256, 36, 3);
  perm_oik_iko<<<dim3(1024), blk, 0, stream>>>(enc_c1_w, wf_enc_c1, 4, 256, 256, 3);
  perm_oik_iko<<<dim3(1024), blk, 0, stream>>>(enc_c2_w, wf_enc_c2, 4, 256, 256, 3);
  perm_oik_iko<<<dim3(1024), blk, 0, stream>>>(down_w, wf_down, 1, 256, 256, 8);
  perm_oik_iko<<<dim3(128), blk, 0, stream>>>(enc_out_w, wf_enc_out, 1, 128, 256, 1);
  perm_oik_iko<<<dim3(128), blk, 0, stream>>>(dec_in_w, wf_dec_in, 1, 256, 128, 1);
  perm_oik_iko<<<dim3(1024), blk, 0, stream>>>(dec_c1_w, wf_dec_c1, 4, 256, 256, 3);
  perm_oik_iko<<<dim3(1024), blk, 0, stream>>>(dec_c2_w, wf_dec_c2, 4, 256, 256, 3);
  perm_decout<<<dim3(64), blk, 0, stream>>>(dec_out_w, wf_dec_out);
  csq_f32<<<dim3(4), blk, 0, stream>>>(codebook, csq);

  const int GN = NB * 8 * 4;  // 512 blocks

  // ---- encoder (fp32), 2 chunks of NB=16 ----
  for (int ci = 0; ci < 2; ci++) {
    int b0 = ci * NB;
    conv_in_k<<<dim3(NB * 32, 4), blk, 0, stream>>>(x + (size_t)b0 * 2048 * 36, wf_enc_in, enc_in_b, f0);
    for (int i = 0; i < 4; i++) {
      gn_part_f32<<<dim3(GN), blk, 0, stream>>>(f0, part_f);
      conv3_gn_k<<<dim3(NB * 16, 4), blk, 0, stream>>>(f0, part_f, enc_gn1_g + i * 256, enc_gn1_b + i * 256,
                                                       wf_enc_c1 + i * 196608, enc_c1_b + i * 256, nullptr, f2);
      gn_part_f32<<<dim3(GN), blk, 0, stream>>>(f2, part_f);
      conv3_gn_k<<<dim3(NB * 16, 4), blk, 0, stream>>>(f2, part_f, enc_gn2_g + i * 256, enc_gn2_b + i * 256,
                                                       wf_enc_c2 + i * 196608, enc_c2_b + i * 256, f0, f0);
    }
    conv_down_k<<<dim3(NB * 8, 4), blk, 0, stream>>>(f0, wf_down, down_b, f2);
    conv1x1_k<<<dim3(NB * 8, 2), blk, 0, stream>>>(f2, wf_enc_out, enc_out_b, zE + (size_t)b0 * 128 * 512, 256, 128);
  }

  // ---- quantize ----
  vq_tiled<<<dim3(256), blk, 0, stream>>>(zE, codebook, csq, codes);
  count_k<<<dim3(64), blk, 0, stream>>>(codes, counts);
  gather_k<<<dim3(512), blk, 0, stream>>>(codebook, codes, zE, zQ, &scal[0]);

  // ---- decoder (fp32), 2 chunks of NB=16 ----
  float* xhat = (float*)d_out;
  for (int ci = 0; ci < 2; ci++) {
    int b0 = ci * NB;
    conv1x1_k<<<dim3(NB * 8, 4), blk, 0, stream>>>(zQ + (size_t)b0 * 128 * 512, wf_dec_in, dec_in_b, dech, 128, 256);
    conv_up_k<<<dim3(NB * 17, 4), blk, 0, stream>>>(dech, up_w, up_b, f0);
    for (int i = 0; i < 4; i++) {
      gn_part_f32<<<dim3(GN), blk, 0, stream>>>(f0, part_f);
      conv3_gn_k<<<dim3(NB * 16, 4), blk, 0, stream>>>(f0, part_f, dec_gn1_g + i * 256, dec_gn1_b + i * 256,
                                                       wf_dec_c1 + i * 196608, dec_c1_b + i * 256, nullptr, f2);
      gn_part_f32<<<dim3(GN), blk, 0, stream>>>(f2, part_f);
      conv3_gn_k<<<dim3(NB * 16, 4), blk, 0, stream>>>(f2, part_f, dec_gn2_g + i * 256, dec_gn2_b + i * 256,
                                                       wf_dec_c2 + i * 196608, dec_c2_b + i * 256, f0, f0);
    }
    conv_out_k<<<dim3(NB * 32), blk, 0, stream>>>(f0, wf_dec_out, dec_out_b, xhat + (size_t)b0 * 2048 * 36);
  }

  // ---- losses / scalars ----
  loss_k<<<dim3(256), blk, 0, stream>>>(x, xhat, mask, scal);
  finalize_k<<<dim3(1), blk, 0, stream>>>(counts, scal, (float*)d_out + 2375680);
  codesf_k<<<dim3(64), blk, 0, stream>>>(codes, (float*)d_out + 2359296);
}

// Round 9
// 8009.276 us; speedup vs baseline: 2.5128x; 1.2732x over previous
//
#include <hip/hip_runtime.h>
#include <cstddef>
#include <cstdint>

// VQ-VAE 1D forward — full fp32 pipeline.
// Codes: reference argmin follows fp32 dist = fl(zsq+csq) - fl(2*zc), first-index ties.
// vq_tiled is BYTE-IDENTICAL to the r7-passing kernel. conv3 per-output FMA chains keep
// the exact r7/r8 expression and ic-order (retile is chain-preserving).
// R9: conv3_gn o-tile 128 (w-read amortization; LDS-pipe was the bound), NB=32 single
// pass, staging address/constant hoisting.
// d_out: x_hat (B,T,36) | codes as float (B,512) | [loss_vq, perplexity, loss_pos, loss_dir]

#define TID ((int)threadIdx.x)
#define NB 32  // whole batch, single pass

__device__ __forceinline__ float silu_f(float y) { return y / (1.f + expf(-y)); }

// ================= weight prep =================
__global__ void perm_oik_iko(const float* __restrict__ src, float* __restrict__ dst,
                             int R, int O, int I, int K) {
  int n = R * O * I * K;
  for (int idx = blockIdx.x * blockDim.x + TID; idx < n; idx += gridDim.x * blockDim.x) {
    int o = idx % O;
    int k = (idx / O) % K;
    int i = (idx / (O * K)) % I;
    int r = idx / (O * K * I);
    dst[idx] = src[((r * O + o) * I + i) * K + k];
  }
}

__global__ void perm_decout(const float* __restrict__ src, float* __restrict__ dst) {
  int n = 256 * 36 * 4;
  for (int idx = blockIdx.x * blockDim.x + TID; idx < n; idx += gridDim.x * blockDim.x) {
    int k = idx & 3;
    int o = (idx >> 2) % 36;
    int i = idx / 144;
    dst[idx] = (k < 3) ? src[(o * 256 + i) * 3 + k] : 0.f;
  }
}

__global__ void zero_k(float* p, int n) {
  int i = blockIdx.x * blockDim.x + TID;
  if (i < n) p[i] = 0.f;
}

// csq[j] = fp32 sequential sum of fl(c*c)
__global__ void csq_f32(const float* __restrict__ cb, float* __restrict__ csq) {
  int j = blockIdx.x * blockDim.x + TID;
  if (j < 1024) {
    float s = 0.f;
    for (int c = 0; c < 128; c++) { float v = cb[j * 128 + c]; s += v * v; }
    csq[j] = s;
  }
}

// ================= GroupNorm stats (apply fused into conv3) =================
__global__ __launch_bounds__(256) void gn_part_f32(const float* __restrict__ in, float* __restrict__ part) {
  int bg = blockIdx.x >> 2, q = blockIdx.x & 3;
  const float4* src = (const float4*)(in + ((size_t)bg << 16) + ((size_t)q << 14));
  float s1 = 0.f, s2 = 0.f;
  for (int f = TID; f < 4096; f += 256) {
    float4 v = src[f];
    s1 += v.x + v.y + v.z + v.w;
    s2 += v.x * v.x + v.y * v.y + v.z * v.z + v.w * v.w;
  }
  __shared__ float r1[256], r2[256];
  r1[TID] = s1; r2[TID] = s2;
  __syncthreads();
  for (int st = 128; st > 0; st >>= 1) {
    if (TID < st) { r1[TID] += r1[TID + st]; r2[TID] += r2[TID + st]; }
    __syncthreads();
  }
  if (TID == 0) { part[blockIdx.x * 2] = r1[0]; part[blockIdx.x * 2 + 1] = r2[0]; }
}

// ================= fp32 convs =================
// input conv 36->256, k=3. grid=(NB*32,4)
__global__ __launch_bounds__(256) void conv_in_k(const float* __restrict__ x, const float* __restrict__ wT,
                                                 const float* __restrict__ bias, float* __restrict__ out) {
  int b = blockIdx.x >> 5;
  int t0 = (blockIdx.x & 31) << 6;
  int o0 = blockIdx.y << 6;
  int tx = TID & 15, oy = TID >> 4;
  __shared__ float ins[36][68];
  __shared__ float wsl[36 * 192];
  for (int idx = TID; idx < 36 * 66; idx += 256) {
    int i = idx % 36, c = idx / 36;
    int t = t0 - 1 + c;
    float v = 0.f;
    if (t >= 0 && t < 2048) v = x[((size_t)(b * 2048 + t)) * 36 + i];
    ins[i][c] = v;
  }
  for (int idx = TID; idx < 36 * 192; idx += 256) {
    int o = idx & 63;
    int kk = (idx >> 6) % 3;
    int i = idx / 192;
    wsl[idx] = wT[(i * 3 + kk) * 256 + o0 + o];
  }
  __syncthreads();
  float acc[4][4];
#pragma unroll
  for (int m = 0; m < 4; m++)
#pragma unroll
    for (int n = 0; n < 4; n++) acc[m][n] = 0.f;
  for (int i = 0; i < 36; i++) {
    float xv[6];
    float4 x4 = *(const float4*)&ins[i][tx << 2];
    xv[0] = x4.x; xv[1] = x4.y; xv[2] = x4.z; xv[3] = x4.w;
    xv[4] = ins[i][(tx << 2) + 4];
    xv[5] = ins[i][(tx << 2) + 5];
    const float* wrow = &wsl[i * 192];
    float wv[3][4];
    *(float4*)wv[0] = *(const float4*)&wrow[oy << 2];
    *(float4*)wv[1] = *(const float4*)&wrow[64 + (oy << 2)];
    *(float4*)wv[2] = *(const float4*)&wrow[128 + (oy << 2)];
#pragma unroll
    for (int m = 0; m < 4; m++)
#pragma unroll
      for (int n = 0; n < 4; n++)
        acc[m][n] += wv[0][m] * xv[n] + wv[1][m] * xv[n + 1] + wv[2][m] * xv[n + 2];
  }
  int obase = o0 + (oy << 2);
#pragma unroll
  for (int m = 0; m < 4; m++) {
    int o = obase + m;
    float bv = bias[o];
    size_t rowo = (((size_t)((b << 8) + o)) << 11) + t0 + (tx << 2);
#pragma unroll
    for (int n = 0; n < 4; n++) out[rowo + n] = acc[m][n] + bv;
  }
}

// k=3 conv 256->256 with fused GN+SiLU input. o-tile 128 (two 64-halves),
// t-tile 128 (two 64-halves), ic-chunk 16. grid=(NB*16, 2).
// Per-output FMA chain identical to r7/r8 (same expression, ic ascending).
__global__ __launch_bounds__(256) void conv3_gn_k(const float* __restrict__ in, const float* __restrict__ part,
                                                  const float* __restrict__ gamma, const float* __restrict__ beta,
                                                  const float* __restrict__ wT, const float* __restrict__ bias,
                                                  const float* __restrict__ src, float* __restrict__ out) {
  int b = blockIdx.x >> 4;
  int t0 = (blockIdx.x & 15) << 7;
  int o0 = blockIdx.y << 7;
  int tx = TID & 15, oy = TID >> 4;
  __shared__ float ins[16][132];
  __shared__ float wsl[3 * 16 * 128];
  float accA[4][4], accB[4][4], accC[4][4], accD[4][4];
#pragma unroll
  for (int m = 0; m < 4; m++)
#pragma unroll
    for (int n = 0; n < 4; n++) { accA[m][n] = 0.f; accB[m][n] = 0.f; accC[m][n] = 0.f; accD[m][n] = 0.f; }
  for (int ic0 = 0; ic0 < 256; ic0 += 16) {
    int g = ic0 >> 5;
    const float* pp = part + ((size_t)((b << 3) + g)) * 8;
    float s1 = pp[0] + pp[2] + pp[4] + pp[6];
    float s2 = pp[1] + pp[3] + pp[5] + pp[7];
    float mu = s1 * (1.f / 65536.f);
    float var = s2 * (1.f / 65536.f) - mu * mu;
    float rs = rsqrtf(var + 1e-5f);
    __syncthreads();
    // stage x: row r = oy (16 rows), 16 lanes per row, per-row constants hoisted
    {
      int ch = ic0 + oy;
      float a = rs * gamma[ch];
      float bb = beta[ch] - mu * a;
      const float* grow = in + (((size_t)((b << 8) + ch)) << 11);
#pragma unroll
      for (int q = 0; q < 9; q++) {
        int c = tx + (q << 4);
        if (c < 132) {
          int t = t0 - 1 + c;
          float v = 0.f;
          if (t >= 0 && t < 2048) {
            float h = grow[t];
            float y = h * a + bb;
            v = y / (1.f + expf(-y));
          }
          ins[oy][c] = v;
        }
      }
    }
    // stage w: layout wsl[(kk*16+i)*128 + o], 1536 float4s
    for (int idx4 = TID; idx4 < 1536; idx4 += 256) {
      int o4 = (idx4 & 31) << 2;
      int i = (idx4 >> 5) & 15;
      int kk = idx4 >> 9;
      *(float4*)&wsl[(((kk << 4) + i) << 7) + o4] =
          *(const float4*)&wT[((ic0 + i) * 3 + kk) * 256 + o0 + o4];
    }
    __syncthreads();
#pragma unroll 2
    for (int i = 0; i < 16; i++) {
      float xv[6], xw[6];
      *(float4*)&xv[0] = *(const float4*)&ins[i][tx << 2];
      *(float2*)&xv[4] = *(const float2*)&ins[i][(tx << 2) + 4];
      *(float4*)&xw[0] = *(const float4*)&ins[i][64 + (tx << 2)];
      *(float2*)&xw[4] = *(const float2*)&ins[i][64 + (tx << 2) + 4];
      float wv[3][4], wb[3][4];
#pragma unroll
      for (int kk = 0; kk < 3; kk++) {
        const float* wrow = &wsl[((kk << 4) + i) << 7];
        *(float4*)wv[kk] = *(const float4*)&wrow[oy << 2];
        *(float4*)wb[kk] = *(const float4*)&wrow[64 + (oy << 2)];
      }
#pragma unroll
      for (int m = 0; m < 4; m++)
#pragma unroll
        for (int n = 0; n < 4; n++) {
          accA[m][n] += wv[0][m] * xv[n] + wv[1][m] * xv[n + 1] + wv[2][m] * xv[n + 2];
          accB[m][n] += wv[0][m] * xw[n] + wv[1][m] * xw[n + 1] + wv[2][m] * xw[n + 2];
          accC[m][n] += wb[0][m] * xv[n] + wb[1][m] * xv[n + 1] + wb[2][m] * xv[n + 2];
          accD[m][n] += wb[0][m] * xw[n] + wb[1][m] * xw[n + 1] + wb[2][m] * xw[n + 2];
        }
    }
  }
#pragma unroll
  for (int m = 0; m < 4; m++) {
    int oA = o0 + (oy << 2) + m;
    int oC = oA + 64;
    float bvA = bias[oA], bvC = bias[oC];
    size_t rowA = (((size_t)((b << 8) + oA)) << 11) + t0 + (tx << 2);
    size_t rowC = (((size_t)((b << 8) + oC)) << 11) + t0 + (tx << 2);
#pragma unroll
    for (int n = 0; n < 4; n++) {
      float v = accA[m][n] + bvA;
      if (src) v += src[rowA + n];
      out[rowA + n] = v;
    }
#pragma unroll
    for (int n = 0; n < 4; n++) {
      float v = accB[m][n] + bvA;
      if (src) v += src[rowA + 64 + n];
      out[rowA + 64 + n] = v;
    }
#pragma unroll
    for (int n = 0; n < 4; n++) {
      float v = accC[m][n] + bvC;
      if (src) v += src[rowC + n];
      out[rowC + n] = v;
    }
#pragma unroll
    for (int n = 0; n < 4; n++) {
      float v = accD[m][n] + bvC;
      if (src) v += src[rowC + 64 + n];
      out[rowC + 64 + n] = v;
    }
  }
}

// down conv k=8 stride 4, Tout=512. grid=(NB*8,4)
__global__ __launch_bounds__(256) void conv_down_k(const float* __restrict__ in, const float* __restrict__ wT,
                                                   const float* __restrict__ bias, float* __restrict__ out) {
  int b = blockIdx.x >> 3;
  int to0 = (blockIdx.x & 7) << 6;
  int o0 = blockIdx.y << 6;
  int tx = TID & 15, oy = TID >> 4;
  __shared__ float ins[16][264];
  __shared__ float wsl[16 * 512];
  float acc[4][4];
#pragma unroll
  for (int m = 0; m < 4; m++)
#pragma unroll
    for (int n = 0; n < 4; n++) acc[m][n] = 0.f;
  for (int ic0 = 0; ic0 < 256; ic0 += 16) {
    __syncthreads();
    for (int idx = TID; idx < 16 * 260; idx += 256) {
      int r = idx / 260, c = idx % 260;
      int s = (to0 << 2) - 2 + c;
      float v = 0.f;
      if (s >= 0 && s < 2048) v = in[(((size_t)((b << 8) + ic0 + r)) << 11) + s];
      ins[r][c] = v;
    }
    for (int idx = TID; idx < 16 * 512; idx += 256) {
      int o = idx & 63;
      int kk = (idx >> 6) & 7;
      int i = idx >> 9;
      wsl[idx] = wT[((ic0 + i) * 8 + kk) * 256 + o0 + o];
    }
    __syncthreads();
#pragma unroll 2
    for (int i = 0; i < 16; i++) {
      float xv[20];
#pragma unroll
      for (int q = 0; q < 5; q++) *(float4*)&xv[q * 4] = *(const float4*)&ins[i][(tx << 4) + (q << 2)];
      float wv[8][4];
#pragma unroll
      for (int kk = 0; kk < 8; kk++) *(float4*)wv[kk] = *(const float4*)&wsl[(i << 9) + (kk << 6) + (oy << 2)];
#pragma unroll
      for (int n = 0; n < 4; n++)
#pragma unroll
        for (int kk = 0; kk < 8; kk++) {
          float xval = xv[(n << 2) + kk];
#pragma unroll
          for (int m = 0; m < 4; m++) acc[m][n] += wv[kk][m] * xval;
        }
    }
  }
  int obase = o0 + (oy << 2);
#pragma unroll
  for (int m = 0; m < 4; m++) {
    int o = obase + m;
    float bv = bias[o];
    size_t rowo = (((size_t)((b << 8) + o)) << 9) + to0 + (tx << 2);
#pragma unroll
    for (int n = 0; n < 4; n++) out[rowo + n] = acc[m][n] + bv;
  }
}

// 1x1 conv, T=512. grid=(NB*8, O/64)
__global__ __launch_bounds__(256) void conv1x1_k(const float* __restrict__ in, const float* __restrict__ wIO,
                                                 const float* __restrict__ bias, float* __restrict__ out,
                                                 int Kc, int O) {
  int b = blockIdx.x >> 3;
  int t0 = (blockIdx.x & 7) << 6;
  int o0 = blockIdx.y << 6;
  int tx = TID & 15, oy = TID >> 4;
  __shared__ float xs[32][64];
  __shared__ float wsd[32][64];
  float acc[4][4];
#pragma unroll
  for (int m = 0; m < 4; m++)
#pragma unroll
    for (int n = 0; n < 4; n++) acc[m][n] = 0.f;
  for (int ic0 = 0; ic0 < Kc; ic0 += 32) {
    __syncthreads();
    for (int idx = TID; idx < 2048; idx += 256) {
      int r = idx >> 6, c = idx & 63;
      xs[r][c] = in[((size_t)(b * Kc + ic0 + r) << 9) + t0 + c];
      wsd[r][c] = wIO[(ic0 + r) * O + o0 + c];
    }
    __syncthreads();
#pragma unroll 8
    for (int i = 0; i < 32; i++) {
      float4 xvv = *(const float4*)&xs[i][tx << 2];
      float4 wvv = *(const float4*)&wsd[i][oy << 2];
      float xv[4] = {xvv.x, xvv.y, xvv.z, xvv.w};
      float wv[4] = {wvv.x, wvv.y, wvv.z, wvv.w};
#pragma unroll
      for (int m = 0; m < 4; m++)
#pragma unroll
        for (int n = 0; n < 4; n++) acc[m][n] += wv[m] * xv[n];
    }
  }
#pragma unroll
  for (int m = 0; m < 4; m++) {
    int o = o0 + (oy << 2) + m;
    float bv = bias[o];
    size_t rowo = ((size_t)(b * O + o) << 9) + t0 + (tx << 2);
#pragma unroll
    for (int n = 0; n < 4; n++) out[rowo + n] = acc[m][n] + bv;
  }
}

// ===== VQ tiled: BYTE-IDENTICAL to r7-passing kernel — do not touch =====
__global__ __launch_bounds__(256) void vq_tiled(const float* __restrict__ zE,
                                                const float* __restrict__ cb,
                                                const float* __restrict__ csq,
                                                int* __restrict__ codes) {
  int b = blockIdx.x >> 3;
  int t0 = (blockIdx.x & 7) << 6;
  int cq = TID & 15, pq = TID >> 4;
  __shared__ float Zs[128][66];
  __shared__ float Cs[64][129];
  __shared__ float zsqs[64];
  __shared__ float bd[64][17];
  __shared__ int bix[64][17];
  for (int idx = TID; idx < 128 * 64; idx += 256) {
    int c = idx >> 6, p = idx & 63;
    Zs[c][p] = zE[((size_t)(b * 128 + c) << 9) + t0 + p];
  }
  __syncthreads();
  if (TID < 64) {
    float s = 0.f;
    for (int c = 0; c < 128; c++) { float v = Zs[c][TID]; s += v * v; }
    zsqs[TID] = s;
  }
  float best[4];
  int bidx[4];
#pragma unroll
  for (int n = 0; n < 4; n++) { best[n] = 3.4e38f; bidx[n] = 0; }
  const int j0 = cq << 2;
  for (int cg = 0; cg < 16; cg++) {
    __syncthreads();
    for (int idx = TID; idx < 64 * 128; idx += 256) {
      int j = idx >> 7, c = idx & 127;
      Cs[j][c] = cb[((cg << 6) + j) * 128 + c];
    }
    __syncthreads();
    float acc[4][4];
#pragma unroll
    for (int u = 0; u < 4; u++)
#pragma unroll
      for (int n = 0; n < 4; n++) acc[u][n] = 0.f;
    for (int c = 0; c < 128; c++) {
      float4 zv4 = *(const float4*)&Zs[c][pq << 2];
      float zv[4] = {zv4.x, zv4.y, zv4.z, zv4.w};
      float cv[4];
#pragma unroll
      for (int u = 0; u < 4; u++) cv[u] = Cs[j0 + u][c];
#pragma unroll
      for (int u = 0; u < 4; u++)
#pragma unroll
        for (int n = 0; n < 4; n++) acc[u][n] += zv[n] * cv[u];
    }
#pragma unroll
    for (int u = 0; u < 4; u++) {
      int code = (cg << 6) + j0 + u;
      float cs_ = csq[code];
#pragma unroll
      for (int n = 0; n < 4; n++) {
        float A = zsqs[(pq << 2) + n] + cs_;
        float B = 2.0f * acc[u][n];
        float d = A - B;
        if (d < best[n]) { best[n] = d; bidx[n] = code; }
      }
    }
  }
  __syncthreads();
#pragma unroll
  for (int n = 0; n < 4; n++) { bd[(pq << 2) + n][cq] = best[n]; bix[(pq << 2) + n][cq] = bidx[n]; }
  __syncthreads();
  if (TID < 64) {
    float bb = bd[TID][0];
    int bj = bix[TID][0];
    for (int q = 1; q < 16; q++) {
      float d = bd[TID][q];
      int j = bix[TID][q];
      if (d < bb || (d == bb && j < bj)) { bb = d; bj = j; }
    }
    codes[(b << 9) + t0 + TID] = bj;
  }
}

// ================= VQ bookkeeping =================
__global__ void count_k(const int* __restrict__ codes, float* __restrict__ counts) {
  int n = blockIdx.x * blockDim.x + TID;
  if (n < 16384) atomicAdd(&counts[codes[n]], 1.f);
}

__global__ __launch_bounds__(256) void gather_k(const float* __restrict__ cb, const int* __restrict__ codes,
                                                const float* __restrict__ zE, float* __restrict__ zQ,
                                                float* __restrict__ vqsum) {
  double part = 0.;
  const int total = 32 * 128 * 512;
  for (int idx = blockIdx.x * blockDim.x + TID; idx < total; idx += gridDim.x * blockDim.x) {
    int t = idx & 511;
    int c = (idx >> 9) & 127;
    int b = idx >> 16;
    int code = codes[(b << 9) + t];
    float q = cb[code * 128 + c];
    double d = (double)q - (double)zE[idx];
    zQ[idx] = q;
    part += d * d;
  }
  __shared__ double red[256];
  red[TID] = part;
  __syncthreads();
  for (int st = 128; st > 0; st >>= 1) {
    if (TID < st) red[TID] += red[TID + st];
    __syncthreads();
  }
  if (TID == 0) atomicAdd(vqsum, (float)red[0]);
}

// ================= decoder-only convs =================
__global__ __launch_bounds__(256) void conv_up_k(const float* __restrict__ in, const float* __restrict__ w,
                                                 const float* __restrict__ bias, float* __restrict__ out) {
  int b = blockIdx.x / 17;
  int s0 = (blockIdx.x % 17) << 5;
  int o0 = blockIdx.y << 6;
  int tx = TID & 15, oy = TID >> 4;
  __shared__ float ins[16][36];
  __shared__ float wsl[16 * 512];
  float acc[2][4][4];
#pragma unroll
  for (int j = 0; j < 2; j++)
#pragma unroll
    for (int m = 0; m < 4; m++)
#pragma unroll
      for (int r = 0; r < 4; r++) acc[j][m][r] = 0.f;
  for (int ic0 = 0; ic0 < 256; ic0 += 16) {
    __syncthreads();
    for (int idx = TID; idx < 16 * 34; idx += 256) {
      int r = idx / 34, c = idx % 34;
      int s = s0 - 1 + c;
      float v = 0.f;
      if (s >= 0 && s < 512) v = in[(((size_t)((b << 8) + ic0 + r)) << 9) + s];
      ins[r][c] = v;
    }
    for (int idx = TID; idx < 8192; idx += 256) {
      int rr = idx & 3;
      int o = (idx >> 2) & 63;
      int h = (idx >> 8) & 1;
      int i = idx >> 9;
      wsl[idx] = w[(((size_t)(ic0 + i)) << 11) + ((size_t)(o0 + o) << 3) + (h << 2) + rr];
    }
    __syncthreads();
#pragma unroll 2
    for (int i = 0; i < 16; i++) {
      float x0 = ins[i][2 * tx], x1 = ins[i][2 * tx + 1], x2 = ins[i][2 * tx + 2];
#pragma unroll
      for (int m = 0; m < 4; m++) {
        int om = (oy << 2) + m;
        float4 wa4 = *(const float4*)&wsl[(i << 9) + (om << 2)];
        float4 wb4 = *(const float4*)&wsl[(i << 9) + 256 + (om << 2)];
        float wa[4] = {wa4.x, wa4.y, wa4.z, wa4.w};
        float wb[4] = {wb4.x, wb4.y, wb4.z, wb4.w};
#pragma unroll
        for (int r = 0; r < 4; r++) {
          acc[0][m][r] += x1 * wa[r] + x0 * wb[r];
          acc[1][m][r] += x2 * wa[r] + x1 * wb[r];
        }
      }
    }
  }
#pragma unroll
  for (int j = 0; j < 2; j++) {
    int s1 = s0 + (tx << 1) + j;
#pragma unroll
    for (int m = 0; m < 4; m++) {
      int o = o0 + (oy << 2) + m;
      float bv = bias[o];
#pragma unroll
      for (int r = 0; r < 4; r++) {
        int t = (s1 << 2) + r - 2;
        if (t >= 0 && t < 2048) out[(((size_t)((b << 8) + o)) << 11) + t] = acc[j][m][r] + bv;
      }
    }
  }
}

__global__ __launch_bounds__(256) void conv_out_k(const float* __restrict__ in, const float* __restrict__ wP,
                                                  const float* __restrict__ bias, float* __restrict__ xhat) {
  int b = blockIdx.x >> 5;
  int t0 = (blockIdx.x & 31) << 6;
  int tx = TID & 63, oy = TID >> 6;
  __shared__ float ins[32][68];
  __shared__ float wsl[32 * 144];
  float acc[9];
#pragma unroll
  for (int m = 0; m < 9; m++) acc[m] = 0.f;
  for (int ic0 = 0; ic0 < 256; ic0 += 32) {
    __syncthreads();
    for (int idx = TID; idx < 32 * 66; idx += 256) {
      int r = idx / 66, c = idx % 66;
      int t = t0 - 1 + c;
      float v = 0.f;
      if (t >= 0 && t < 2048) v = in[(((size_t)((b << 8) + ic0 + r)) << 11) + t];
      ins[r][c] = v;
    }
    for (int idx = TID; idx < 32 * 144; idx += 256) {
      wsl[idx] = wP[ic0 * 144 + idx];
    }
    __syncthreads();
#pragma unroll 4
    for (int i = 0; i < 32; i++) {
      float x0 = ins[i][tx], x1 = ins[i][tx + 1], x2 = ins[i][tx + 2];
#pragma unroll
      for (int m = 0; m < 9; m++) {
        int o = oy * 9 + m;
        float4 wv = *(const float4*)&wsl[(i * 36 + o) << 2];
        acc[m] += wv.x * x0 + wv.y * x1 + wv.z * x2;
      }
    }
  }
  size_t orow = ((size_t)(b << 11) + t0 + tx) * 36;
#pragma unroll
  for (int m = 0; m < 9; m++) {
    int o = oy * 9 + m;
    xhat[orow + o] = acc[m] + bias[o];
  }
}

// ================= losses =================
__global__ __launch_bounds__(256) void loss_k(const float* __restrict__ x, const float* __restrict__ xh,
                                              const float* __restrict__ mask, float* __restrict__ scal) {
  float pos = 0.f, dir = 0.f, ms = 0.f;
  for (int n = blockIdx.x * blockDim.x + TID; n < 65536; n += gridDim.x * blockDim.x) {
    const float* xp = x + (size_t)n * 36;
    const float* hp = xh + (size_t)n * 36;
    float a[36], h[36];
#pragma unroll
    for (int d4 = 0; d4 < 36; d4 += 4) {
      *(float4*)&a[d4] = *(const float4*)&xp[d4];
      *(float4*)&h[d4] = *(const float4*)&hp[d4];
    }
#pragma unroll
    for (int d = 0; d < 36; d++) {
      if (d < 21 || (d >= 27 && d < 30)) {
        float df = h[d] - a[d];
        float ad = fabsf(df);
        pos += (ad < 1.f) ? 0.5f * df * df : ad - 0.5f;
      }
    }
    float mL = mask[2 * (size_t)n], mR = mask[2 * (size_t)n + 1];
    const int vb[4] = {21, 24, 30, 33};
    float mv[4] = {mL, mL, mR, mR};
#pragma unroll
    for (int v = 0; v < 4; v++) {
      int o = vb[v];
      float ax = a[o], ay = a[o + 1], az = a[o + 2];
      float hx = h[o], hy = h[o + 1], hz = h[o + 2];
      float an = sqrtf(ax * ax + ay * ay + az * az) + 1e-8f;
      float hn = sqrtf(hx * hx + hy * hy + hz * hz) + 1e-8f;
      float cs = (ax * hx + ay * hy + az * hz) / (an * hn);
      dir += (1.f - cs) * mv[v];
    }
    ms += 2.f * (mL + mR);
  }
  __shared__ float rp[256], rd[256], rm[256];
  rp[TID] = pos; rd[TID] = dir; rm[TID] = ms;
  __syncthreads();
  for (int st = 128; st > 0; st >>= 1) {
    if (TID < st) { rp[TID] += rp[TID + st]; rd[TID] += rd[TID + st]; rm[TID] += rm[TID + st]; }
    __syncthreads();
  }
  if (TID == 0) {
    atomicAdd(&scal[1], rp[0]);
    atomicAdd(&scal[2], rd[0]);
    atomicAdd(&scal[3], rm[0]);
  }
}

__global__ __launch_bounds__(256) void finalize_k(const float* __restrict__ counts, const float* __restrict__ scal,
                                                  float* __restrict__ tail) {
  __shared__ float red[256];
  float s = 0.f;
  for (int j = TID; j < 1024; j += 256) {
    float avg = counts[j] * (1.f / 16384.f);
    s += avg * logf(avg + 1e-10f);
  }
  red[TID] = s;
  __syncthreads();
  for (int st = 128; st > 0; st >>= 1) {
    if (TID < st) red[TID] += red[TID + st];
    __syncthreads();
  }
  if (TID == 0) {
    tail[0] = 1.25f * scal[0] * (1.f / 2097152.f);
    tail[1] = expf(-red[0]);
    tail[2] = scal[1] * (1.f / 65536.f);
    tail[3] = scal[2] / fmaxf(scal[3], 1.f);
  }
}

__global__ void codesf_k(const int* __restrict__ codes, float* __restrict__ o) {
  int n = blockIdx.x * blockDim.x + TID;
  if (n < 16384) o[n] = (float)codes[n];
}

// ================= host =================
extern "C" void kernel_launch(void* const* d_in, const int* in_sizes, int n_in,
                              void* d_out, int out_size, void* d_ws, size_t ws_size,
                              hipStream_t stream) {
  const float* x = (const float*)d_in[0];
  const float* mask = (const float*)d_in[1];
  const float* enc_in_w = (const float*)d_in[2];
  const float* enc_in_b = (const float*)d_in[3];
  const float* enc_gn1_g = (const float*)d_in[4];
  const float* enc_gn1_b = (const float*)d_in[5];
  const float* enc_c1_w = (const float*)d_in[6];
  const float* enc_c1_b = (const float*)d_in[7];
  const float* enc_gn2_g = (const float*)d_in[8];
  const float* enc_gn2_b = (const float*)d_in[9];
  const float* enc_c2_w = (const float*)d_in[10];
  const float* enc_c2_b = (const float*)d_in[11];
  const float* down_w = (const float*)d_in[12];
  const float* down_b = (const float*)d_in[13];
  const float* enc_out_w = (const float*)d_in[14];
  const float* enc_out_b = (const float*)d_in[15];
  const float* codebook = (const float*)d_in[16];
  const float* dec_in_w = (const float*)d_in[17];
  const float* dec_in_b = (const float*)d_in[18];
  const float* up_w = (const float*)d_in[19];
  const float* up_b = (const float*)d_in[20];
  const float* dec_gn1_g = (const float*)d_in[21];
  const float* dec_gn1_b = (const float*)d_in[22];
  const float* dec_c1_w = (const float*)d_in[23];
  const float* dec_c1_b = (const float*)d_in[24];
  const float* dec_gn2_g = (const float*)d_in[25];
  const float* dec_gn2_b = (const float*)d_in[26];
  const float* dec_c2_w = (const float*)d_in[27];
  const float* dec_c2_b = (const float*)d_in[28];
  const float* dec_out_w = (const float*)d_in[29];
  const float* dec_out_b = (const float*)d_in[30];

  char* W = (char*)d_ws;
  float* zE = (float*)(W + 0);                        // 8,388,608
  float* zQ = (float*)(W + 8388608);                  // 8,388,608
  int* codes = (int*)(W + 16777216);                  // 65,536
  float* counts = (float*)(W + 16842752);             // 4,096
  float* scal = (float*)(W + 16846848);               // 32
  float* csq = (float*)(W + 16846880);                // 4,096
  float* part_f = (float*)(W + 16850976);             // 8,192 (32 b x 8 g x 4 q x 2)
  float* wf_enc_in = (float*)(W + 16859168);          // 110,592
  float* wf_enc_c1 = (float*)(W + 16969760);          // 3,145,728
  float* wf_enc_c2 = (float*)(W + 20115488);          // 3,145,728
  float* wf_down = (float*)(W + 23261216);            // 2,097,152
  float* wf_enc_out = (float*)(W + 25358368);         // 131,072
  float* wf_dec_in = (float*)(W + 25489440);          // 131,072
  float* wf_dec_c1 = (float*)(W + 25620512);          // 3,145,728
  float* wf_dec_c2 = (float*)(W + 28766240);          // 3,145,728
  float* wf_dec_out = (float*)(W + 31911968);         // 147,456
  // big region @48MiB: f0, f2 (67.1MB each, 32 batches) + dech (16.8MB)
  float* f0 = (float*)(W + 50331648);
  float* f2 = (float*)(W + 50331648 + (size_t)67108864);
  float* dech = (float*)(W + 50331648 + 2 * (size_t)67108864);

  dim3 blk(256);
  zero_k<<<dim3(5), blk, 0, stream>>>(counts, 1032);
  perm_oik_iko<<<dim3(128), blk, 0, stream>>>(enc_in_w, wf_enc_in, 1, 256, 36, 3);
  perm_oik_iko<<<dim3(1024), blk, 0, stream>>>(enc_c1_w, wf_enc_c1, 4, 256, 256, 3);
  perm_oik_iko<<<dim3(1024), blk, 0, stream>>>(enc_c2_w, wf_enc_c2, 4, 256, 256, 3);
  perm_oik_iko<<<dim3(1024), blk, 0, stream>>>(down_w, wf_down, 1, 256, 256, 8);
  perm_oik_iko<<<dim3(128), blk, 0, stream>>>(enc_out_w, wf_enc_out, 1, 128, 256, 1);
  perm_oik_iko<<<dim3(128), blk, 0, stream>>>(dec_in_w, wf_dec_in, 1, 256, 128, 1);
  perm_oik_iko<<<dim3(1024), blk, 0, stream>>>(dec_c1_w, wf_dec_c1, 4, 256, 256, 3);
  perm_oik_iko<<<dim3(1024), blk, 0, stream>>>(dec_c2_w, wf_dec_c2, 4, 256, 256, 3);
  perm_decout<<<dim3(64), blk, 0, stream>>>(dec_out_w, wf_dec_out);
  csq_f32<<<dim3(4), blk, 0, stream>>>(codebook, csq);

  const int GN = NB * 8 * 4;  // 1024 blocks

  // ---- encoder (fp32), whole batch ----
  conv_in_k<<<dim3(NB * 32, 4), blk, 0, stream>>>(x, wf_enc_in, enc_in_b, f0);
  for (int i = 0; i < 4; i++) {
    gn_part_f32<<<dim3(GN), blk, 0, stream>>>(f0, part_f);
    conv3_gn_k<<<dim3(NB * 16, 2), blk, 0, stream>>>(f0, part_f, enc_gn1_g + i * 256, enc_gn1_b + i * 256,
                                                     wf_enc_c1 + i * 196608, enc_c1_b + i * 256, nullptr, f2);
    gn_part_f32<<<dim3(GN), blk, 0, stream>>>(f2, part_f);
    conv3_gn_k<<<dim3(NB * 16, 2), blk, 0, stream>>>(f2, part_f, enc_gn2_g + i * 256, enc_gn2_b + i * 256,
                                                     wf_enc_c2 + i * 196608, enc_c2_b + i * 256, f0, f0);
  }
  conv_down_k<<<dim3(NB * 8, 4), blk, 0, stream>>>(f0, wf_down, down_b, f2);
  conv1x1_k<<<dim3(NB * 8, 2), blk, 0, stream>>>(f2, wf_enc_out, enc_out_b, zE, 256, 128);

  // ---- quantize ----
  vq_tiled<<<dim3(256), blk, 0, stream>>>(zE, codebook, csq, codes);
  count_k<<<dim3(64), blk, 0, stream>>>(codes, counts);
  gather_k<<<dim3(512), blk, 0, stream>>>(codebook, codes, zE, zQ, &scal[0]);

  // ---- decoder (fp32), whole batch ----
  float* xhat = (float*)d_out;
  conv1x1_k<<<dim3(NB * 8, 4), blk, 0, stream>>>(zQ, wf_dec_in, dec_in_b, dech, 128, 256);
  conv_up_k<<<dim3(NB * 17, 4), blk, 0, stream>>>(dech, up_w, up_b, f0);
  for (int i = 0; i < 4; i++) {
    gn_part_f32<<<dim3(GN), blk, 0, stream>>>(f0, part_f);
    conv3_gn_k<<<dim3(NB * 16, 2), blk, 0, stream>>>(f0, part_f, dec_gn1_g + i * 256, dec_gn1_b + i * 256,
                                                     wf_dec_c1 + i * 196608, dec_c1_b + i * 256, nullptr, f2);
    gn_part_f32<<<dim3(GN), blk, 0, stream>>>(f2, part_f);
    conv3_gn_k<<<dim3(NB * 16, 2), blk, 0, stream>>>(f2, part_f, dec_gn2_g + i * 256, dec_gn2_b + i * 256,
                                                     wf_dec_c2 + i * 196608, dec_c2_b + i * 256, f0, f0);
  }
  conv_out_k<<<dim3(NB * 32), blk, 0, stream>>>(f0, wf_dec_out, dec_out_b, xhat);

  // ---- losses / scalars ----
  loss_k<<<dim3(256), blk, 0, stream>>>(x, xhat, mask, scal);
  finalize_k<<<dim3(1), blk, 0, stream>>>(counts, scal, (float*)d_out + 2375680);
  codesf_k<<<dim3(64), blk, 0, stream>>>(codes, (float*)d_out + 2359296);
}